// Round 12
// baseline (429.264 us; speedup 1.0000x reference)
//
#include <hip/hip_runtime.h>

typedef unsigned long long u64;
typedef unsigned int u32;
typedef _Float16 f16;
typedef _Float16 f16x8 __attribute__((ext_vector_type(8)));
typedef _Float16 f16x4 __attribute__((ext_vector_type(4)));
typedef float f32x4 __attribute__((ext_vector_type(4)));

#define MFMA16(a, b, c) __builtin_amdgcn_mfma_f32_16x16x32_f16(a, b, c, 0, 0, 0)

#define NROWS 32768
#define DIN   1024
#define DM    512
#define KC    1024
#define SPLIT_SC  1024.0f
#define CHSZ  32
#define MAXCH 2048
#define MARGIN 0.5f
#define ZB    8

// ---- output float offsets ----
#define OFF_XR   0ull
#define OFF_CL   33554432ull
#define OFF_IDX  33554433ull
#define OFF_ZE   33587201ull   // base %4==1 -> scalar access only
#define OFF_ZQ   50364417ull
#define OFF_NE   67141633ull
#define OFF_NCS  67665921ull
#define OFF_NEMA 67666945ull

// ---- workspace byte offsets ----
#define WS_FLAG    2097152ull  // int[32768] flagged rows
#define WS_ZNORM   2359296ull
#define WS_IDX     2490368ull
#define WS_COUNTS  2621440ull
#define WS_STARTS  2625536ull
#define WS_OFFW    2629632ull
#define WS_ROWLIST 2633728ull
#define WS_CSD     2764800ull
#define WS_ENORM   2769920ull
#define WS2_CAND   (4ull<<20)   // u64[32768*16] = 4MB; reused as ED after resolve
#define WS2_WT1    (36ull<<20)
#define WS2_DT     (38ull<<20)
#define WS2_E1     (39ull<<20)
#define WS3_CHPFX  (41ull<<20)
#define WS3_CHCODE ((41ull<<20) + 8192)
#define WS3_CPART  ((41ull<<20) + 16384)
#define WS3_NFLAG  ((41ull<<20) + 32768)
#define WS3_PART   ((41ull<<20) + 65536)

// x16 staging lives in the dead x_recon output region at byte offset 32MB
// (z1 occupies [0,32MB); x_recon region is 128MB; both dead before k_gatherx)

// ============================================================================
// LDS helpers (proven patterns)
// ============================================================================
__device__ inline void gload16(const f16* g, f16* l) {
  __builtin_amdgcn_global_load_lds((const __attribute__((address_space(1))) void*)g,
                                   (__attribute__((address_space(3))) void*)l, 16, 0, 0);
}

__device__ inline f16x8 ldfrag32(const f16* p, int row, int kc) {
  return *(const f16x8*)(p + row * 32 + ((kc ^ ((row >> 1) & 3)) << 3));
}

__device__ inline void stage32(const f16* gbase, int ld, int row0, int k0,
                               f16* lds, int t) {
  int r = t >> 2, c = t & 3;
  int cs = c ^ ((r >> 1) & 3);
  gload16(gbase + (size_t)(row0 + r) * ld + k0 + cs * 8, lds + t * 8);
}

__device__ inline void stageA256(const f16* gbase, int ld, int row0, int k0,
                                 f16* lds, int t) {
#pragma unroll
  for (int h = 0; h < 2; h++) {
    int e = t + h * 512;
    int r = e >> 2, c = e & 3;
    int cs = c ^ ((r >> 1) & 3);
    gload16(gbase + (size_t)(row0 + r) * ld + k0 + cs * 8, lds + e * 8);
  }
}

// monotone float->u32 map and inverse (argmin packing)
__device__ inline u32 enc_score(float s) {
  u32 kb = __float_as_uint(s);
  return (kb & 0x80000000u) ? ~kb : (kb | 0x80000000u);
}
__device__ inline float dec_score(u32 u) {
  u32 b = (u & 0x80000000u) ? (u & 0x7fffffffu) : ~u;
  return __uint_as_float(b);
}

// ============================================================================
// fused prep: [0,512) enc_w^T f16 | [512,1024) dec_w^T | [1024,1536) emb f16
// [1536,1792) enorm | [1792,1796) counts=0 + nflag=0 | [1796,3844) x -> f16
// ============================================================================
__global__ __launch_bounds__(256) void k_prep(const float* __restrict__ enc_w,
                                              const float* __restrict__ dec_w,
                                              const float* __restrict__ emb,
                                              const float* __restrict__ x,
                                              f16* __restrict__ wt1,
                                              f16* __restrict__ dT,
                                              f16* __restrict__ e1,
                                              f16* __restrict__ x16,
                                              float* __restrict__ enorm,
                                              int* __restrict__ counts,
                                              int* __restrict__ nflag) {
  __shared__ float tile[32][33];
  int bid = blockIdx.x, t = threadIdx.x;
  if (bid < 1024) {
    const float* W;
    f16* o1;
    int K, N, bx, by;
    if (bid < 512) {
      W = enc_w; o1 = wt1; K = DIN; N = DM;
      bx = bid & 15; by = bid >> 4;
    } else {
      int b2 = bid - 512;
      W = dec_w; o1 = dT; K = DM; N = DIN;
      bx = b2 & 31; by = b2 >> 5;
    }
    int tx = t & 31, ty = t >> 5;
    int nb = bx * 32, kb = by * 32;
#pragma unroll
    for (int i = 0; i < 32; i += 8)
      tile[ty + i][tx] = W[(size_t)(kb + ty + i) * N + nb + tx];
    __syncthreads();
#pragma unroll
    for (int i = 0; i < 32; i += 8)
      o1[(size_t)(nb + ty + i) * K + kb + tx] = (f16)tile[tx][ty + i];
  } else if (bid < 1536) {
    int tid = (bid - 1024) * 256 + t;
    for (int i = tid; i < KC * DM; i += 131072) e1[i] = (f16)emb[i];
  } else if (bid < 1792) {
    int k = (bid - 1536) * 4 + (t >> 6), lane = t & 63;
    float s = 0.f;
#pragma unroll
    for (int j = 0; j < 8; j++) {
      float v = emb[(size_t)k * DM + lane + j * 64];
      s = fmaf(v, v, s);
    }
#pragma unroll
    for (int m = 1; m < 64; m <<= 1) s += __shfl_xor(s, m, 64);
    if (lane == 0) enorm[k] = s;
  } else if (bid < 1796) {
    int i = (bid - 1792) * 256 + t;
    if (i < KC) counts[i] = 0;
    if (bid == 1792 && t == 0) nflag[0] = 0;
  } else {
    size_t base = (size_t)(bid - 1796) * 16384;
    for (int i = t; i < 4096; i += 256) {
      float4 v = *(const float4*)(x + base + (size_t)i * 4);
      f16 h4[4] = {(f16)v.x, (f16)v.y, (f16)v.z, (f16)v.w};
      *(f16x4*)(x16 + base + (size_t)i * 4) = *(f16x4*)h4;
    }
  }
}

// ============================================================================
// encoder GEMM 1-product f16 (dist4-structure clone): 256x128 block, wave
// 64x64, BK=32, K=1024, 3-buf single-barrier, gload_lds staging of x16+wt1.
// ============================================================================
__global__ __launch_bounds__(512, 4) void k_genc1p(const f16* __restrict__ x16,
                                                   const f16* __restrict__ wt1,
                                                   const float* __restrict__ bias,
                                                   float* __restrict__ dst) {
  __shared__ __align__(16) f16 A[3][256 * 32];   // 48KB
  __shared__ __align__(16) f16 B[3][128 * 32];   // 24KB
  int t = threadIdx.x, lane = t & 63, wid = t >> 6;
  int wr = wid >> 1, wc = wid & 1;
  int l = blockIdx.x;
  int xcd = l & 7, s = l >> 3, ct = s & 3;
  int p = ((s >> 2) << 3) | xcd;                 // 128 row-panels of 256
  int r0 = p * 256, c0 = ct * 128;
  f32x4 acc[4][4] = {};
  int kc = lane >> 4;

  stageA256(x16, DIN, r0, 0, A[0], t);
  stage32(wt1, DIN, c0, 0, B[0], t);

  for (int it = 0; it < 32; ++it) {
    int buf = it % 3;
    if (it < 31) {
      int nb = (it + 1) % 3;
      int k0n = (it + 1) * 32;
      stageA256(x16, DIN, r0, k0n, A[nb], t);
      stage32(wt1, DIN, c0, k0n, B[nb], t);
      asm volatile("s_waitcnt vmcnt(3)" ::: "memory");
    } else {
      asm volatile("s_waitcnt vmcnt(0)" ::: "memory");
    }
    __builtin_amdgcn_sched_barrier(0);
    __builtin_amdgcn_s_barrier();
    asm volatile("" ::: "memory");
    f16x8 af[4], bf[4];
#pragma unroll
    for (int m = 0; m < 4; m++)
      af[m] = ldfrag32(A[buf], wr * 64 + m * 16 + (lane & 15), kc);
#pragma unroll
    for (int n = 0; n < 4; n++)
      bf[n] = ldfrag32(B[buf], wc * 64 + n * 16 + (lane & 15), kc);
#pragma unroll
    for (int m = 0; m < 4; m++)
#pragma unroll
      for (int n = 0; n < 4; n++) acc[m][n] = MFMA16(af[m], bf[n], acc[m][n]);
  }

#pragma unroll
  for (int m = 0; m < 4; m++)
#pragma unroll
    for (int n = 0; n < 4; n++)
#pragma unroll
      for (int j = 0; j < 4; j++) {
        int row = r0 + wr * 64 + m * 16 + (lane >> 4) * 4 + j;
        int col = c0 + wc * 64 + n * 16 + (lane & 15);
        dst[(size_t)row * DM + col] = acc[m][n][j] + bias[col];
      }
}

// ============================================================================
// distance GEMM v4 (unchanged, proven): 256x128, wave 64x64, 3-buf 1-barrier
// ============================================================================
__global__ __launch_bounds__(512, 4) void k_dist4(const f16* __restrict__ z1,
                                                  const f16* __restrict__ e1,
                                                  const float* __restrict__ enorm,
                                                  u64* __restrict__ cand) {
  __shared__ __align__(16) f16 A[3][256 * 32];
  __shared__ __align__(16) f16 B[3][128 * 32];
  int t = threadIdx.x, lane = t & 63, wid = t >> 6;
  int wr = wid >> 1, wc = wid & 1;
  int l = blockIdx.x;
  int xcd = l & 7, s = l >> 3, ct = s & 7;
  int p = ((s >> 3) << 3) | xcd;
  int r0 = p * 256, c0 = ct * 128;
  f32x4 acc[4][4] = {};
  int kc = lane >> 4;

  stageA256(z1, DM, r0, 0, A[0], t);
  stage32(e1, DM, c0, 0, B[0], t);

  for (int it = 0; it < 16; ++it) {
    int buf = it % 3;
    if (it < 15) {
      int nb = (it + 1) % 3;
      int k0n = (it + 1) * 32;
      stageA256(z1, DM, r0, k0n, A[nb], t);
      stage32(e1, DM, c0, k0n, B[nb], t);
      asm volatile("s_waitcnt vmcnt(3)" ::: "memory");
    } else {
      asm volatile("s_waitcnt vmcnt(0)" ::: "memory");
    }
    __builtin_amdgcn_sched_barrier(0);
    __builtin_amdgcn_s_barrier();
    asm volatile("" ::: "memory");
    f16x8 af[4], bf[4];
#pragma unroll
    for (int m = 0; m < 4; m++)
      af[m] = ldfrag32(A[buf], wr * 64 + m * 16 + (lane & 15), kc);
#pragma unroll
    for (int n = 0; n < 4; n++)
      bf[n] = ldfrag32(B[buf], wc * 64 + n * 16 + (lane & 15), kc);
#pragma unroll
    for (int m = 0; m < 4; m++)
#pragma unroll
      for (int n = 0; n < 4; n++) acc[m][n] = MFMA16(af[m], bf[n], acc[m][n]);
  }

  __syncthreads();
  u64 (*cand_s)[4] = (u64 (*)[4])(&A[0][0]);
  float en[4];
#pragma unroll
  for (int n = 0; n < 4; n++)
    en[n] = enorm[c0 + wc * 64 + n * 16 + (lane & 15)];
#pragma unroll
  for (int m = 0; m < 4; m++)
#pragma unroll
    for (int j = 0; j < 4; j++) {
      int r_l = wr * 64 + m * 16 + (lane >> 4) * 4 + j;
      u64 lo = ~0ull, hi = ~0ull;
#pragma unroll
      for (int n = 0; n < 4; n++) {
        int col = c0 + wc * 64 + n * 16 + (lane & 15);
        float sc = fmaf(-2.0f, acc[m][n][j], en[n]);
        u64 k = ((u64)enc_score(sc) << 32) | (u32)col;
        if (k < lo) { hi = lo; lo = k; }
        else if (k < hi) { hi = k; }
      }
#pragma unroll
      for (int msk = 1; msk < 16; msk <<= 1) {
        u64 lo2 = __shfl_xor(lo, msk, 64);
        u64 hi2 = __shfl_xor(hi, msk, 64);
        u64 nlo = lo < lo2 ? lo : lo2;
        u64 losr = lo < lo2 ? lo2 : lo;
        u64 nh = hi < hi2 ? hi : hi2;
        hi = losr < nh ? losr : nh;
        lo = nlo;
      }
      if ((lane & 15) == 0) {
        cand_s[r_l][wc * 2] = lo;
        cand_s[r_l][wc * 2 + 1] = hi;
      }
    }
  __syncthreads();
  if (t < 256) {
    u64 b0 = ~0ull, b1 = ~0ull;
#pragma unroll
    for (int i = 0; i < 4; i++) {
      u64 k = cand_s[t][i];
      if (k < b0) { b1 = b0; b0 = k; }
      else if (k < b1) { b1 = k; }
    }
    u64* dst = cand + ((size_t)(r0 + t) * 16 + ct * 2);
    dst[0] = b0;
    dst[1] = b1;
  }
}

// ============================================================================
// resolve v2: preliminary argmin from 16 keys; flag rows with >1 candidate
// within MARGIN to a global list (fixed by k_zfix); prelim idx/zq/counts;
// approx commit partials.
// ============================================================================
__global__ __launch_bounds__(256) void k_resolve(const u64* __restrict__ cand,
                                                 const float* __restrict__ znorm,
                                                 const float* __restrict__ emb,
                                                 float* __restrict__ out,
                                                 int* __restrict__ idxws,
                                                 int* __restrict__ counts,
                                                 float* __restrict__ cpart,
                                                 int* __restrict__ nflag,
                                                 int* __restrict__ flaglist) {
  int t = threadIdx.x, bid = blockIdx.x;
  int r0 = bid * 16;
  __shared__ u64 key_s[256];
  __shared__ int idx_s[16];
  __shared__ float commit_s[16];
  key_s[t] = cand[(size_t)r0 * 16 + t];
  __syncthreads();

  if (t < 16) {
    int R = r0 + t;
    u64 best = ~0ull;
#pragma unroll
    for (int i = 0; i < 16; i++) {
      u64 k = key_s[t * 16 + i];
      best = k < best ? k : best;
    }
    float smin = dec_score((u32)(best >> 32));
    float thr = smin + MARGIN;
    int nc = 0;
#pragma unroll
    for (int i = 0; i < 16; i++)
      if (dec_score((u32)(key_s[t * 16 + i] >> 32)) <= thr) nc++;
    int idx = (int)(u32)(best & 0xffffffffull);
    idx_s[t] = idx;
    commit_s[t] = znorm[R] + smin;
    if (nc > 1) {
      int pz = atomicAdd(nflag, 1);
      flaglist[pz] = R;
    }
    out[OFF_IDX + R] = (float)idx;
    idxws[R] = idx;
    atomicAdd(counts + idx, 1);
  }
  __syncthreads();
  for (int rr = 0; rr < 16; rr++) {
    int R = r0 + rr;
    const float* e = emb + (size_t)idx_s[rr] * DM;
    float* zq = out + OFF_ZQ + (size_t)R * DM;
#pragma unroll
    for (int j = 0; j < 2; j++) {
      int c = t + j * 256;
      zq[c] = e[c];
    }
  }
  if (t == 0) {
    float s = 0.f;
#pragma unroll
    for (int i = 0; i < 16; i++) s += commit_s[i];
    cpart[bid] = s;
  }
}

// ============================================================================
// zfix: for flagged rows, recompute z exactly in fp32 (x@enc_w+b, LN) in
// batches of 8 rows per block (enc_w read once per batch), rescore the 16
// candidates exactly, and fix idx/z_q/counts where the winner changed.
// ============================================================================
__global__ __launch_bounds__(512) void k_zfix(const int* __restrict__ nflag,
                                              const int* __restrict__ flaglist,
                                              const float* __restrict__ x,
                                              const float* __restrict__ enc_w,
                                              const float* __restrict__ enc_b,
                                              const float* __restrict__ g,
                                              const float* __restrict__ bb,
                                              const u64* __restrict__ cand,
                                              const float* __restrict__ emb,
                                              const float* __restrict__ enorm,
                                              float* __restrict__ out,
                                              int* __restrict__ idxws,
                                              int* __restrict__ counts) {
  __shared__ float xs[ZB][1024];   // 32KB
  __shared__ float zs[ZB][512];    // 16KB
  __shared__ float red[ZB][8], red2[ZB][8];
  __shared__ int rows_s[ZB];
  int nf = nflag[0];
  int t = threadIdx.x, lane = t & 63, wid = t >> 6;
  for (int b = blockIdx.x; b * ZB < nf; b += 128) {
    int base = b * ZB;
    int cnt = min(ZB, nf - base);
    if (t < ZB) rows_s[t] = flaglist[base + min(t, cnt - 1)];
    __syncthreads();
    for (int i = t; i < cnt * 256; i += 512) {
      int r8 = i >> 8, c4 = (i & 255) << 2;
      *(float4*)&xs[r8][c4] = *(const float4*)(x + (size_t)rows_s[r8] * DIN + c4);
    }
    __syncthreads();
    float acc[ZB];
#pragma unroll
    for (int r = 0; r < ZB; r++) acc[r] = 0.f;
    for (int k = 0; k < 1024; k += 4) {
      float w0 = enc_w[(size_t)k * DM + t];
      float w1 = enc_w[(size_t)(k + 1) * DM + t];
      float w2 = enc_w[(size_t)(k + 2) * DM + t];
      float w3 = enc_w[(size_t)(k + 3) * DM + t];
#pragma unroll
      for (int r = 0; r < ZB; r++) {
        float4 xv = *(const float4*)&xs[r][k];
        acc[r] = fmaf(xv.x, w0, acc[r]);
        acc[r] = fmaf(xv.y, w1, acc[r]);
        acc[r] = fmaf(xv.z, w2, acc[r]);
        acc[r] = fmaf(xv.w, w3, acc[r]);
      }
    }
    float bsum = enc_b[t];
#pragma unroll
    for (int r = 0; r < ZB; r++) {
      acc[r] += bsum;
      float s = acc[r], sq = acc[r] * acc[r];
#pragma unroll
      for (int m = 1; m < 64; m <<= 1) {
        s += __shfl_xor(s, m, 64);
        sq += __shfl_xor(sq, m, 64);
      }
      if (lane == 0) { red[r][wid] = s; red2[r][wid] = sq; }
    }
    __syncthreads();
    float gg = g[t], bv = bb[t];
#pragma unroll
    for (int r = 0; r < ZB; r++) {
      float s = 0.f, sq = 0.f;
#pragma unroll
      for (int w8 = 0; w8 < 8; w8++) { s += red[r][w8]; sq += red2[r][w8]; }
      float mu = s * (1.f / DM);
      float var = sq * (1.f / DM) - mu * mu;
      float rs = rsqrtf(var + 1e-5f);
      zs[r][t] = (acc[r] - mu) * rs * gg + bv;
    }
    __syncthreads();
    if (wid < cnt) {
      int R = rows_s[wid];
      float zreg[8];
      float zn = 0.f;
#pragma unroll
      for (int j = 0; j < 8; j++) {
        zreg[j] = zs[wid][lane + j * 64];
        zn = fmaf(zreg[j], zreg[j], zn);
      }
#pragma unroll
      for (int m = 1; m < 64; m <<= 1) zn += __shfl_xor(zn, m, 64);
      u64 bestk = ~0ull;
      for (int i = 0; i < 16; i++) {
        u64 kk = cand[(size_t)R * 16 + i];
        int c = (int)(u32)(kk & 0xffffffffull);
        const float* e = emb + (size_t)c * DM;
        float dot = 0.f;
#pragma unroll
        for (int j = 0; j < 8; j++) dot = fmaf(zreg[j], e[lane + j * 64], dot);
#pragma unroll
        for (int m = 1; m < 64; m <<= 1) dot += __shfl_xor(dot, m, 64);
        float d = fmaf(-2.f, dot, zn) + enorm[c];
        u64 pk = ((u64)enc_score(d) << 32) | (u32)c;
        bestk = pk < bestk ? pk : bestk;
      }
      int newidx = (int)(u32)(bestk & 0xffffffffull);
      int oldidx = idxws[R];
      if (newidx != oldidx) {
        if (lane == 0) {
          idxws[R] = newidx;
          out[OFF_IDX + R] = (float)newidx;
          atomicSub(counts + oldidx, 1);
          atomicAdd(counts + newidx, 1);
        }
        const float* e = emb + (size_t)newidx * DM;
        float* zq = out + OFF_ZQ + (size_t)R * DM;
#pragma unroll
        for (int j = 0; j < 8; j++) zq[lane + j * 64] = e[lane + j * 64];
      }
    }
    __syncthreads();
  }
}

// ============================================================================
// ED GEMM (unchanged): ED = e1 @ dT + dec_b; x_recon[r] = ED[idx[r]]
// ============================================================================
__global__ __launch_bounds__(512) void k_edgemm(const f16* __restrict__ e1,
                                                const f16* __restrict__ dT,
                                                const float* __restrict__ bias,
                                                float* __restrict__ ED) {
  __shared__ __align__(16) f16 A[3][128 * 32], B[3][128 * 32];
  int t = threadIdx.x, lane = t & 63, wid = t >> 6;
  int wm = wid >> 2, wn = wid & 3;
  int r0 = (blockIdx.x >> 3) * 128, c0 = (blockIdx.x & 7) * 128;
  f32x4 acc[4][2] = {};
  int kc = lane >> 4;

  stage32(e1, DM, r0, 0, A[0], t);
  stage32(dT, DM, c0, 0, B[0], t);

  for (int it = 0; it < 16; ++it) {
    int buf = it % 3;
    if (it < 15) {
      int nb = (it + 1) % 3;
      int k0n = (it + 1) * 32;
      stage32(e1, DM, r0, k0n, A[nb], t);
      stage32(dT, DM, c0, k0n, B[nb], t);
      asm volatile("s_waitcnt vmcnt(2)" ::: "memory");
    } else {
      asm volatile("s_waitcnt vmcnt(0)" ::: "memory");
    }
    __builtin_amdgcn_sched_barrier(0);
    __builtin_amdgcn_s_barrier();
    asm volatile("" ::: "memory");
    f16x8 af[4], bf[2];
#pragma unroll
    for (int m = 0; m < 4; m++)
      af[m] = ldfrag32(A[buf], wm * 64 + m * 16 + (lane & 15), kc);
#pragma unroll
    for (int n = 0; n < 2; n++)
      bf[n] = ldfrag32(B[buf], wn * 32 + n * 16 + (lane & 15), kc);
#pragma unroll
    for (int m = 0; m < 4; m++)
#pragma unroll
      for (int n = 0; n < 2; n++) acc[m][n] = MFMA16(af[m], bf[n], acc[m][n]);
  }

#pragma unroll
  for (int m = 0; m < 4; m++)
#pragma unroll
    for (int n = 0; n < 2; n++)
#pragma unroll
      for (int j = 0; j < 4; j++) {
        int row = r0 + wm * 64 + m * 16 + (lane >> 4) * 4 + j;
        int col = c0 + wn * 32 + n * 16 + (lane & 15);
        ED[(size_t)row * DIN + col] = acc[m][n][j] + bias[col];
      }
}

__global__ __launch_bounds__(256) void k_gatherx(const int* __restrict__ idxws,
                                                 const float* __restrict__ ED,
                                                 float* __restrict__ xr) {
  int t = threadIdx.x, r0 = blockIdx.x * 16;
  __shared__ int idx_s[16];
  if (t < 16) idx_s[t] = idxws[r0 + t];
  __syncthreads();
  for (int rr = 0; rr < 16; rr++) {
    int R = r0 + rr;
    const float4* src = (const float4*)(ED + (size_t)idx_s[rr] * DIN);
    float4* dst = (float4*)(xr + (size_t)R * DIN);
    dst[t] = src[t];
  }
}

// ============================================================================
// LayerNorm (unchanged): z_e fp32, z1 f16 plane, znorm
// ============================================================================
__global__ __launch_bounds__(256) void k_ln3(float* __restrict__ ze,
                                             const float* __restrict__ g,
                                             const float* __restrict__ b,
                                             f16* __restrict__ z1,
                                             float* __restrict__ znorm) {
  int t = threadIdx.x, lane = t & 63, wid = t >> 6;
  int R = blockIdx.x * 4 + wid;
  float* row = ze + (size_t)R * DM;
  float v[8];
  float s = 0.f, sq = 0.f;
#pragma unroll
  for (int j = 0; j < 8; j++) {
    v[j] = row[lane + j * 64];
    s += v[j];
    sq = fmaf(v[j], v[j], sq);
  }
#pragma unroll
  for (int m = 1; m < 64; m <<= 1) {
    s += __shfl_xor(s, m, 64);
    sq += __shfl_xor(sq, m, 64);
  }
  float mu = s * (1.f / DM);
  float var = sq * (1.f / DM) - mu * mu;
  float rs = rsqrtf(var + 1e-5f);
  float zn = 0.f;
#pragma unroll
  for (int j = 0; j < 8; j++) {
    int c = lane + j * 64;
    float o = (v[j] - mu) * rs * g[c] + b[c];
    row[c] = o;
    z1[(size_t)R * DM + c] = (f16)o;
    zn = fmaf(o, o, zn);
  }
#pragma unroll
  for (int m = 1; m < 64; m <<= 1) zn += __shfl_xor(zn, m, 64);
  if (lane == 0) znorm[R] = zn;
}

// ============================================================================
// EMA tail (unchanged, proven)
// ============================================================================
__global__ __launch_bounds__(1024) void k_scan(const int* __restrict__ counts,
                                               const float* __restrict__ cs_in,
                                               float* __restrict__ out,
                                               int* __restrict__ starts,
                                               int* __restrict__ offw,
                                               float* __restrict__ csd,
                                               const float* __restrict__ cpart,
                                               int* __restrict__ chpfx,
                                               int* __restrict__ chcode) {
  __shared__ float f[1024];
  __shared__ int ib[1024];
  int t = threadIdx.x;
  f[t] = cpart[t] + cpart[t + 1024];
  __syncthreads();
  for (int s = 512; s > 0; s >>= 1) {
    if (t < s) f[t] += f[t + s];
    __syncthreads();
  }
  if (t == 0) out[OFF_CL] = f[0] * (1.f / ((float)NROWS * (float)DM));
  __syncthreads();

  int cnt = counts[t];
  float ncs = 0.99f * cs_in[t] + 0.01f * (float)cnt;
  out[OFF_NCS + t] = ncs;
  f[t] = ncs;
  __syncthreads();
  for (int s = 512; s > 0; s >>= 1) {
    if (t < s) f[t] += f[t + s];
    __syncthreads();
  }
  float n = f[0];
  csd[t] = (ncs + 1e-5f) / (n + (float)KC * 1e-5f) * n;
  ib[t] = cnt;
  __syncthreads();
  for (int s = 1; s < 1024; s <<= 1) {
    int y = (t >= s) ? ib[t - s] : 0;
    __syncthreads();
    ib[t] += y;
    __syncthreads();
  }
  int excl = ib[t] - cnt;
  starts[t] = excl;
  offw[t] = excl;
  int nch = (cnt + CHSZ - 1) / CHSZ;
  __syncthreads();
  ib[t] = nch;
  __syncthreads();
  for (int s = 1; s < 1024; s <<= 1) {
    int y = (t >= s) ? ib[t - s] : 0;
    __syncthreads();
    ib[t] += y;
    __syncthreads();
  }
  int chx = ib[t] - nch;
  chpfx[t] = chx;
  if (t == KC - 1) chpfx[KC] = ib[t];
  for (int j = 0; j < nch; j++) chcode[chx + j] = t;
}

__global__ __launch_bounds__(256) void k_scatter(const int* __restrict__ idxws,
                                                 int* __restrict__ offw,
                                                 int* __restrict__ rowlist) {
  int r = blockIdx.x * 256 + threadIdx.x;
  int idx = idxws[r];
  int pos = atomicAdd(offw + idx, 1);
  rowlist[pos] = r;
}

__global__ __launch_bounds__(128) void k_partsum(const int* __restrict__ chpfx,
                                                 const int* __restrict__ chcode,
                                                 const int* __restrict__ starts,
                                                 const int* __restrict__ counts,
                                                 const int* __restrict__ rowlist,
                                                 const float* __restrict__ out,
                                                 float* __restrict__ part) {
  int c = blockIdx.x, t = threadIdx.x;
  if (c >= chpfx[KC]) return;
  int code = chcode[c];
  int j = c - chpfx[code];
  int ofs = starts[code] + j * CHSZ;
  int len = min(CHSZ, counts[code] - j * CHSZ);
  __shared__ int rl[CHSZ];
  if (t < len) rl[t] = rowlist[ofs + t];
  __syncthreads();
  const float* zeb = out + OFF_ZE;
  float a0 = 0.f, a1 = 0.f, a2 = 0.f, a3 = 0.f;
  for (int i = 0; i < len; i++) {
    const float* z = zeb + (size_t)rl[i] * DM;
    a0 += z[t];
    a1 += z[t + 128];
    a2 += z[t + 256];
    a3 += z[t + 384];
  }
  float* pp = part + (size_t)c * DM;
  pp[t] = a0;
  pp[t + 128] = a1;
  pp[t + 256] = a2;
  pp[t + 384] = a3;
}

__global__ __launch_bounds__(128) void k_codesum2(const int* __restrict__ chpfx,
                                                  const float* __restrict__ part,
                                                  const float* __restrict__ ema_in,
                                                  const float* __restrict__ csd,
                                                  float* __restrict__ out) {
  int k = blockIdx.x, t = threadIdx.x;
  int base = chpfx[k], nch = chpfx[k + 1] - base;
  float a0 = 0.f, a1 = 0.f, a2 = 0.f, a3 = 0.f;
  for (int i = 0; i < nch; i++) {
    const float* pp = part + (size_t)(base + i) * DM;
    a0 += pp[t];
    a1 += pp[t + 128];
    a2 += pp[t + 256];
    a3 += pp[t + 384];
  }
  float cs = csd[k];
  float sum[4] = {a0, a1, a2, a3};
#pragma unroll
  for (int j = 0; j < 4; j++) {
    int c = t + j * 128;
    float e = 0.99f * ema_in[(size_t)k * DM + c] + 0.01f * sum[j];
    out[OFF_NEMA + (size_t)k * DM + c] = e;
    out[OFF_NE + (size_t)k * DM + c] = e / cs;
  }
}

// ============================================================================
extern "C" void kernel_launch(void* const* d_in, const int* in_sizes, int n_in,
                              void* d_out, int out_size, void* d_ws, size_t ws_size,
                              hipStream_t stream) {
  (void)in_sizes; (void)n_in; (void)out_size; (void)ws_size;
  const float* x = (const float*)d_in[0];
  const float* enc_w = (const float*)d_in[1];
  const float* enc_b = (const float*)d_in[2];
  const float* ln_g = (const float*)d_in[3];
  const float* ln_b = (const float*)d_in[4];
  const float* dec_w = (const float*)d_in[5];
  const float* dec_b = (const float*)d_in[6];
  const float* emb = (const float*)d_in[7];
  const float* cs_in = (const float*)d_in[8];
  const float* ema_in = (const float*)d_in[9];
  float* out = (float*)d_out;
  char* ws = (char*)d_ws;
  int* flaglist = (int*)(ws + WS_FLAG);
  float* znorm = (float*)(ws + WS_ZNORM);
  int* idxws = (int*)(ws + WS_IDX);
  int* counts = (int*)(ws + WS_COUNTS);
  int* starts = (int*)(ws + WS_STARTS);
  int* offw = (int*)(ws + WS_OFFW);
  int* rowlist = (int*)(ws + WS_ROWLIST);
  float* csd = (float*)(ws + WS_CSD);
  float* enorm = (float*)(ws + WS_ENORM);
  u64* cand = (u64*)(ws + WS2_CAND);
  float* ED = (float*)(ws + WS2_CAND);   // reuses cand region after zfix
  f16* wt1 = (f16*)(ws + WS2_WT1);
  f16* dT = (f16*)(ws + WS2_DT);
  f16* e1 = (f16*)(ws + WS2_E1);
  int* chpfx = (int*)(ws + WS3_CHPFX);
  int* chcode = (int*)(ws + WS3_CHCODE);
  float* cpart = (float*)(ws + WS3_CPART);
  int* nflag = (int*)(ws + WS3_NFLAG);
  float* part = (float*)(ws + WS3_PART);
  f16* z1 = (f16*)out;                             // out bytes [0,32MB)
  f16* x16 = (f16*)((char*)out + (32ull << 20));   // out bytes [32MB,96MB)

  k_prep<<<dim3(3844), dim3(256), 0, stream>>>(enc_w, dec_w, emb, x, wt1, dT,
                                               e1, x16, enorm, counts, nflag);
  k_genc1p<<<dim3(512), dim3(512), 0, stream>>>(x16, wt1, enc_b, out + OFF_ZE);
  k_ln3<<<dim3(8192), dim3(256), 0, stream>>>(out + OFF_ZE, ln_g, ln_b, z1, znorm);
  k_dist4<<<dim3(1024), dim3(512), 0, stream>>>(z1, e1, enorm, cand);
  k_resolve<<<dim3(2048), dim3(256), 0, stream>>>(cand, znorm, emb, out, idxws,
                                                  counts, cpart, nflag, flaglist);
  k_zfix<<<dim3(128), dim3(512), 0, stream>>>(nflag, flaglist, x, enc_w, enc_b,
                                              ln_g, ln_b, cand, emb, enorm, out,
                                              idxws, counts);
  k_edgemm<<<dim3(64), dim3(512), 0, stream>>>(e1, dT, dec_b, ED);
  k_scan<<<dim3(1), dim3(1024), 0, stream>>>(counts, cs_in, out, starts, offw, csd,
                                             cpart, chpfx, chcode);
  k_scatter<<<dim3(NROWS / 256), dim3(256), 0, stream>>>(idxws, offw, rowlist);
  k_partsum<<<dim3(MAXCH), dim3(128), 0, stream>>>(chpfx, chcode, starts, counts,
                                                   rowlist, out, part);
  k_codesum2<<<dim3(KC), dim3(128), 0, stream>>>(chpfx, part, ema_in, csd, out);
  k_gatherx<<<dim3(2048), dim3(256), 0, stream>>>(idxws, ED, out + OFF_XR);
}

// Round 13
// 331.658 us; speedup vs baseline: 1.2943x; 1.2943x over previous
//
#include <hip/hip_runtime.h>

typedef unsigned long long u64;
typedef unsigned int u32;
typedef _Float16 f16;
typedef _Float16 f16x8 __attribute__((ext_vector_type(8)));
typedef float f32x4 __attribute__((ext_vector_type(4)));

#define MFMA16(a, b, c) __builtin_amdgcn_mfma_f32_16x16x32_f16(a, b, c, 0, 0, 0)

#define NROWS 32768
#define DIN   1024
#define DM    512
#define KC    1024
#define SPLIT_SC  1024.0f
#define SPLIT_INV 0.0009765625f
#define CHSZ  32
#define MAXCH 2048
#define MARGIN 0.5f

// ---- output float offsets ----
#define OFF_XR   0ull
#define OFF_CL   33554432ull
#define OFF_IDX  33554433ull
#define OFF_ZE   33587201ull   // base %4==1 -> scalar access only
#define OFF_ZQ   50364417ull
#define OFF_NE   67141633ull
#define OFF_NCS  67665921ull
#define OFF_NEMA 67666945ull

// ---- workspace byte offsets ----
#define WS_ZNORM   2359296ull
#define WS_IDX     2490368ull
#define WS_COUNTS  2621440ull
#define WS_STARTS  2625536ull
#define WS_OFFW    2629632ull
#define WS_ROWLIST 2633728ull
#define WS_CSD     2764800ull
#define WS_ENORM   2769920ull
#define WS2_CAND   (4ull<<20)   // u64[32768*16] = 4MB; reused as ED after resolve
#define WS2_WT1    (36ull<<20)
#define WS2_WT2    (37ull<<20)
#define WS2_DT     (38ull<<20)
#define WS2_E1     (39ull<<20)
#define WS3_CHPFX  (41ull<<20)
#define WS3_CHCODE ((41ull<<20) + 8192)
#define WS3_CPART  ((41ull<<20) + 16384)
#define WS3_PART   ((41ull<<20) + 65536)

// ============================================================================
// LDS helpers (proven patterns)
// ============================================================================
__device__ inline void gload16(const f16* g, f16* l) {
  __builtin_amdgcn_global_load_lds((const __attribute__((address_space(1))) void*)g,
                                   (__attribute__((address_space(3))) void*)l, 16, 0, 0);
}

__device__ inline f16x8 ldfrag32(const f16* p, int row, int kc) {
  return *(const f16x8*)(p + row * 32 + ((kc ^ ((row >> 1) & 3)) << 3));
}

// stage a [128][32] f16 plane (8KB) with 512 threads
__device__ inline void stage32(const f16* gbase, int ld, int row0, int k0,
                               f16* lds, int t) {
  int r = t >> 2, c = t & 3;
  int cs = c ^ ((r >> 1) & 3);
  gload16(gbase + (size_t)(row0 + r) * ld + k0 + cs * 8, lds + t * 8);
}

// stage a [256][32] f16 plane (16KB) with 512 threads (2 x 16B each)
__device__ inline void stageA256(const f16* gbase, int ld, int row0, int k0,
                                 f16* lds, int t) {
#pragma unroll
  for (int h = 0; h < 2; h++) {
    int e = t + h * 512;
    int r = e >> 2, c = e & 3;
    int cs = c ^ ((r >> 1) & 3);
    gload16(gbase + (size_t)(row0 + r) * ld + k0 + cs * 8, lds + e * 8);
  }
}

// monotone float->u32 map and inverse (argmin packing)
__device__ inline u32 enc_score(float s) {
  u32 kb = __float_as_uint(s);
  return (kb & 0x80000000u) ? ~kb : (kb | 0x80000000u);
}
__device__ inline float dec_score(u32 u) {
  u32 b = (u & 0x80000000u) ? (u & 0x7fffffffu) : ~u;
  return __uint_as_float(b);
}

// ============================================================================
// fused prep (round-11 proven)
// ============================================================================
__global__ __launch_bounds__(256) void k_prep(const float* __restrict__ enc_w,
                                              const float* __restrict__ dec_w,
                                              const float* __restrict__ emb,
                                              f16* __restrict__ wt1,
                                              f16* __restrict__ wt2,
                                              f16* __restrict__ dT,
                                              f16* __restrict__ e1,
                                              float* __restrict__ enorm,
                                              int* __restrict__ counts) {
  __shared__ float tile[32][33];
  int bid = blockIdx.x, t = threadIdx.x;
  if (bid < 1024) {
    const float* W;
    f16 *o1, *o2;
    int K, N, bx, by;
    if (bid < 512) {
      W = enc_w; o1 = wt1; o2 = wt2; K = DIN; N = DM;
      bx = bid & 15; by = bid >> 4;
    } else {
      int b2 = bid - 512;
      W = dec_w; o1 = dT; o2 = nullptr; K = DM; N = DIN;
      bx = b2 & 31; by = b2 >> 5;
    }
    int tx = t & 31, ty = t >> 5;
    int nb = bx * 32, kb = by * 32;
#pragma unroll
    for (int i = 0; i < 32; i += 8)
      tile[ty + i][tx] = W[(size_t)(kb + ty + i) * N + nb + tx];
    __syncthreads();
#pragma unroll
    for (int i = 0; i < 32; i += 8) {
      float v = tile[tx][ty + i];
      f16 h = (f16)v;
      size_t o = (size_t)(nb + ty + i) * K + kb + tx;
      o1[o] = h;
      if (o2) o2[o] = (f16)((v - (float)h) * SPLIT_SC);
    }
  } else if (bid < 1536) {
    int tid = (bid - 1024) * 256 + t;
    for (int i = tid; i < KC * DM; i += 131072) e1[i] = (f16)emb[i];
  } else if (bid < 1792) {
    int k = (bid - 1536) * 4 + (t >> 6), lane = t & 63;
    float s = 0.f;
#pragma unroll
    for (int j = 0; j < 8; j++) {
      float v = emb[(size_t)k * DM + lane + j * 64];
      s = fmaf(v, v, s);
    }
#pragma unroll
    for (int m = 1; m < 64; m <<= 1) s += __shfl_xor(s, m, 64);
    if (lane == 0) enorm[k] = s;
  } else {
    int i = (bid - 1792) * 256 + t;
    if (i < KC) counts[i] = 0;
  }
}

// ============================================================================
// encoder GEMM v6: 128x128, BK=32, split-f16 3-product, A AND B double-
// buffered -> ONE barrier per K-step (dist4-style). Convert placed AFTER
// compute in the same phase (safe for any intra-body reordering: foreign
// reads of the written buffer were sealed by the previous barrier).
// Ledger (B staged before av; 2 av-loads + 2 gload_lds per iter):
//   prologue: av(0),B(0),av(1) -> vmcnt(4) retires av(0); GCONV; vmcnt(2)
//             lgkm0 retires B(0); barrier. Enter it=0 with queue av(1)x2.
//   iter it:  stage B(it+1); load av(it+2); compute(it);
//             vmcnt(4) [it=30: vmcnt(2)] retires av(it+1); GCONV->A[(it+1)&1];
//             vmcnt(2) lgkm0 [it=30: vmcnt(0)] retires B(it+1); barrier.
// Accumulation order bit-identical to proven genc4.
// ============================================================================
__global__ __launch_bounds__(512, 4) void k_genc6(const float* __restrict__ x,
                                                  const f16* __restrict__ wt1,
                                                  const f16* __restrict__ wt2,
                                                  const float* __restrict__ bias,
                                                  float* __restrict__ dst) {
  __shared__ __align__(16) f16 A1[2][128 * 32], A2[2][128 * 32];
  __shared__ __align__(16) f16 B1[2][128 * 32], B2[2][128 * 32];
  int t = threadIdx.x, lane = t & 63, wid = t >> 6;
  int wm = wid >> 2, wn = wid & 3;
  int l = blockIdx.x;
  int xcd = l & 7, s = l >> 3, ct = s & 3;
  int p = ((s >> 2) << 3) | xcd;
  int m0 = p * 128, n0 = ct * 128;
  int r = t >> 2, cg = t & 3;
  int cslot = cg ^ ((r >> 1) & 3);
  const float* ax = x + (size_t)(m0 + r) * DIN + cg * 8;
  f32x4 accA[4][2] = {}, accB[4][2] = {};

#define GCONV(v0, v1, buf)                                                  \
  {                                                                         \
    float a_[8] = {v0.x, v0.y, v0.z, v0.w, v1.x, v1.y, v1.z, v1.w};         \
    f16 h1_[8], h2_[8];                                                     \
    _Pragma("unroll") for (int j_ = 0; j_ < 8; j_++) {                      \
      f16 h_ = (f16)a_[j_];                                                 \
      h1_[j_] = h_;                                                         \
      h2_[j_] = (f16)((a_[j_] - (float)h_) * SPLIT_SC);                     \
    }                                                                       \
    *(f16x8*)(A1[buf] + r * 32 + cslot * 8) = *(f16x8*)h1_;                 \
    *(f16x8*)(A2[buf] + r * 32 + cslot * 8) = *(f16x8*)h2_;                 \
  }

#define GCOMP(buf)                                                          \
  {                                                                         \
    int kc_ = lane >> 4;                                                    \
    f16x8 a1f[4], a2f[4], b1f[2], b2f[2];                                   \
    _Pragma("unroll") for (int m_ = 0; m_ < 4; m_++) {                      \
      int row_ = wm * 64 + m_ * 16 + (lane & 15);                           \
      a1f[m_] = ldfrag32(A1[buf], row_, kc_);                               \
      a2f[m_] = ldfrag32(A2[buf], row_, kc_);                               \
    }                                                                       \
    _Pragma("unroll") for (int n_ = 0; n_ < 2; n_++) {                      \
      int row_ = wn * 32 + n_ * 16 + (lane & 15);                           \
      b1f[n_] = ldfrag32(B1[buf], row_, kc_);                               \
      b2f[n_] = ldfrag32(B2[buf], row_, kc_);                               \
    }                                                                       \
    _Pragma("unroll") for (int m_ = 0; m_ < 4; m_++)                        \
      _Pragma("unroll") for (int n_ = 0; n_ < 2; n_++) {                    \
        accA[m_][n_] = MFMA16(a1f[m_], b1f[n_], accA[m_][n_]);              \
        accB[m_][n_] = MFMA16(a1f[m_], b2f[n_], accB[m_][n_]);              \
        accB[m_][n_] = MFMA16(a2f[m_], b1f[n_], accB[m_][n_]);              \
      }                                                                     \
  }

  // prologue
  float4 c0 = *(const float4*)(ax);                 // av(0)
  float4 c1 = *(const float4*)(ax + 4);
  stage32(wt1, DIN, n0, 0, B1[0], t);               // B(0)
  stage32(wt2, DIN, n0, 0, B2[0], t);
  float4 n0v = *(const float4*)(ax + 32);           // av(1)
  float4 n1v = *(const float4*)(ax + 36);
  asm volatile("s_waitcnt vmcnt(4)" ::: "memory");  // av(0) retired
  GCONV(c0, c1, 0);
  asm volatile("s_waitcnt vmcnt(2) lgkmcnt(0)" ::: "memory");  // B(0) retired
  __builtin_amdgcn_sched_barrier(0);
  __builtin_amdgcn_s_barrier();
  asm volatile("" ::: "memory");

  for (int it = 0; it < 32; ++it) {
    if (it + 1 < 32) {                              // B(it+1) -> dbuf
      stage32(wt1, DIN, n0, (it + 1) * 32, B1[(it + 1) & 1], t);
      stage32(wt2, DIN, n0, (it + 1) * 32, B2[(it + 1) & 1], t);
    }
    float4 f0, f1;
    if (it + 2 < 32) {                              // av(it+2) regs
      f0 = *(const float4*)(ax + (it + 2) * 32);
      f1 = *(const float4*)(ax + (it + 2) * 32 + 4);
    }
    GCOMP(it & 1);                                  // compute(it)
    if (it + 1 < 32) {                              // convert av(it+1)
      if (it <= 29) {
        asm volatile("s_waitcnt vmcnt(4)" ::: "memory");   // retire av(it+1)
      } else {
        asm volatile("s_waitcnt vmcnt(2)" ::: "memory");   // it==30
      }
      GCONV(n0v, n1v, (it + 1) & 1);
      if (it <= 29) {
        asm volatile("s_waitcnt vmcnt(2) lgkmcnt(0)" ::: "memory");  // B(it+1)
      } else {
        asm volatile("s_waitcnt vmcnt(0) lgkmcnt(0)" ::: "memory");
      }
      __builtin_amdgcn_sched_barrier(0);
      __builtin_amdgcn_s_barrier();
      asm volatile("" ::: "memory");
    }
    n0v = f0; n1v = f1;
  }
#undef GCONV
#undef GCOMP

#pragma unroll
  for (int m = 0; m < 4; m++)
#pragma unroll
    for (int n = 0; n < 2; n++)
#pragma unroll
      for (int j = 0; j < 4; j++) {
        int row = m0 + wm * 64 + m * 16 + (lane >> 4) * 4 + j;
        int col = n0 + wn * 32 + n * 16 + (lane & 15);
        dst[(size_t)row * DM + col] = accA[m][n][j] + SPLIT_INV * accB[m][n][j] + bias[col];
      }
}

// ============================================================================
// distance GEMM v4 (unchanged, proven): 256x128, wave 64x64, 3-buf 1-barrier
// ============================================================================
__global__ __launch_bounds__(512, 4) void k_dist4(const f16* __restrict__ z1,
                                                  const f16* __restrict__ e1,
                                                  const float* __restrict__ enorm,
                                                  u64* __restrict__ cand) {
  __shared__ __align__(16) f16 A[3][256 * 32];
  __shared__ __align__(16) f16 B[3][128 * 32];
  int t = threadIdx.x, lane = t & 63, wid = t >> 6;
  int wr = wid >> 1, wc = wid & 1;
  int l = blockIdx.x;
  int xcd = l & 7, s = l >> 3, ct = s & 7;
  int p = ((s >> 3) << 3) | xcd;
  int r0 = p * 256, c0 = ct * 128;
  f32x4 acc[4][4] = {};
  int kc = lane >> 4;

  stageA256(z1, DM, r0, 0, A[0], t);
  stage32(e1, DM, c0, 0, B[0], t);

  for (int it = 0; it < 16; ++it) {
    int buf = it % 3;
    if (it < 15) {
      int nb = (it + 1) % 3;
      int k0n = (it + 1) * 32;
      stageA256(z1, DM, r0, k0n, A[nb], t);
      stage32(e1, DM, c0, k0n, B[nb], t);
      asm volatile("s_waitcnt vmcnt(3)" ::: "memory");
    } else {
      asm volatile("s_waitcnt vmcnt(0)" ::: "memory");
    }
    __builtin_amdgcn_sched_barrier(0);
    __builtin_amdgcn_s_barrier();
    asm volatile("" ::: "memory");
    f16x8 af[4], bf[4];
#pragma unroll
    for (int m = 0; m < 4; m++)
      af[m] = ldfrag32(A[buf], wr * 64 + m * 16 + (lane & 15), kc);
#pragma unroll
    for (int n = 0; n < 4; n++)
      bf[n] = ldfrag32(B[buf], wc * 64 + n * 16 + (lane & 15), kc);
#pragma unroll
    for (int m = 0; m < 4; m++)
#pragma unroll
      for (int n = 0; n < 4; n++) acc[m][n] = MFMA16(af[m], bf[n], acc[m][n]);
  }

  __syncthreads();
  u64 (*cand_s)[4] = (u64 (*)[4])(&A[0][0]);
  float en[4];
#pragma unroll
  for (int n = 0; n < 4; n++)
    en[n] = enorm[c0 + wc * 64 + n * 16 + (lane & 15)];
#pragma unroll
  for (int m = 0; m < 4; m++)
#pragma unroll
    for (int j = 0; j < 4; j++) {
      int r_l = wr * 64 + m * 16 + (lane >> 4) * 4 + j;
      u64 lo = ~0ull, hi = ~0ull;
#pragma unroll
      for (int n = 0; n < 4; n++) {
        int col = c0 + wc * 64 + n * 16 + (lane & 15);
        float sc = fmaf(-2.0f, acc[m][n][j], en[n]);
        u64 k = ((u64)enc_score(sc) << 32) | (u32)col;
        if (k < lo) { hi = lo; lo = k; }
        else if (k < hi) { hi = k; }
      }
#pragma unroll
      for (int msk = 1; msk < 16; msk <<= 1) {
        u64 lo2 = __shfl_xor(lo, msk, 64);
        u64 hi2 = __shfl_xor(hi, msk, 64);
        u64 nlo = lo < lo2 ? lo : lo2;
        u64 losr = lo < lo2 ? lo2 : lo;
        u64 nh = hi < hi2 ? hi : hi2;
        hi = losr < nh ? losr : nh;
        lo = nlo;
      }
      if ((lane & 15) == 0) {
        cand_s[r_l][wc * 2] = lo;
        cand_s[r_l][wc * 2 + 1] = hi;
      }
    }
  __syncthreads();
  if (t < 256) {
    u64 b0 = ~0ull, b1 = ~0ull;
#pragma unroll
    for (int i = 0; i < 4; i++) {
      u64 k = cand_s[t][i];
      if (k < b0) { b1 = b0; b0 = k; }
      else if (k < b1) { b1 = k; }
    }
    u64* dst = cand + ((size_t)(r0 + t) * 16 + ct * 2);
    dst[0] = b0;
    dst[1] = b1;
  }
}

// ============================================================================
// ED GEMM (unchanged): ED = e1 @ dT + dec_b; x_recon[r] = ED[idx[r]]
// ============================================================================
__global__ __launch_bounds__(512) void k_edgemm(const f16* __restrict__ e1,
                                                const f16* __restrict__ dT,
                                                const float* __restrict__ bias,
                                                float* __restrict__ ED) {
  __shared__ __align__(16) f16 A[3][128 * 32], B[3][128 * 32];
  int t = threadIdx.x, lane = t & 63, wid = t >> 6;
  int wm = wid >> 2, wn = wid & 3;
  int r0 = (blockIdx.x >> 3) * 128, c0 = (blockIdx.x & 7) * 128;
  f32x4 acc[4][2] = {};
  int kc = lane >> 4;

  stage32(e1, DM, r0, 0, A[0], t);
  stage32(dT, DM, c0, 0, B[0], t);

  for (int it = 0; it < 16; ++it) {
    int buf = it % 3;
    if (it < 15) {
      int nb = (it + 1) % 3;
      int k0n = (it + 1) * 32;
      stage32(e1, DM, r0, k0n, A[nb], t);
      stage32(dT, DM, c0, k0n, B[nb], t);
      asm volatile("s_waitcnt vmcnt(2)" ::: "memory");
    } else {
      asm volatile("s_waitcnt vmcnt(0)" ::: "memory");
    }
    __builtin_amdgcn_sched_barrier(0);
    __builtin_amdgcn_s_barrier();
    asm volatile("" ::: "memory");
    f16x8 af[4], bf[2];
#pragma unroll
    for (int m = 0; m < 4; m++)
      af[m] = ldfrag32(A[buf], wm * 64 + m * 16 + (lane & 15), kc);
#pragma unroll
    for (int n = 0; n < 2; n++)
      bf[n] = ldfrag32(B[buf], wn * 32 + n * 16 + (lane & 15), kc);
#pragma unroll
    for (int m = 0; m < 4; m++)
#pragma unroll
      for (int n = 0; n < 2; n++) acc[m][n] = MFMA16(af[m], bf[n], acc[m][n]);
  }

#pragma unroll
  for (int m = 0; m < 4; m++)
#pragma unroll
    for (int n = 0; n < 2; n++)
#pragma unroll
      for (int j = 0; j < 4; j++) {
        int row = r0 + wm * 64 + m * 16 + (lane >> 4) * 4 + j;
        int col = c0 + wn * 32 + n * 16 + (lane & 15);
        ED[(size_t)row * DIN + col] = acc[m][n][j] + bias[col];
      }
}

__global__ __launch_bounds__(256) void k_gatherx(const int* __restrict__ idxws,
                                                 const float* __restrict__ ED,
                                                 float* __restrict__ xr) {
  int t = threadIdx.x, r0 = blockIdx.x * 16;
  __shared__ int idx_s[16];
  if (t < 16) idx_s[t] = idxws[r0 + t];
  __syncthreads();
  for (int rr = 0; rr < 16; rr++) {
    int R = r0 + rr;
    const float4* src = (const float4*)(ED + (size_t)idx_s[rr] * DIN);
    float4* dst = (float4*)(xr + (size_t)R * DIN);
    dst[t] = src[t];
  }
}

// ============================================================================
// resolve (round-11 proven, with exact in-kernel rescore)
// ============================================================================
__global__ __launch_bounds__(256) void k_resolve(const u64* __restrict__ cand,
                                                 const float* __restrict__ znorm,
                                                 const float* __restrict__ enorm,
                                                 const float* __restrict__ emb,
                                                 float* __restrict__ out,
                                                 int* __restrict__ idxws,
                                                 int* __restrict__ counts,
                                                 float* __restrict__ cpart) {
  int t = threadIdx.x, bid = blockIdx.x;
  int r0 = bid * 16;
  __shared__ u64 key_s[256];
  __shared__ int idx_s[16];
  __shared__ float commit_s[16];
  __shared__ int flagcnt_s;
  __shared__ int flagrow_s[16];
  key_s[t] = cand[(size_t)r0 * 16 + t];
  if (t == 0) flagcnt_s = 0;
  __syncthreads();

  if (t < 16) {
    u64 best = ~0ull;
#pragma unroll
    for (int i = 0; i < 16; i++) {
      u64 k = key_s[t * 16 + i];
      best = k < best ? k : best;
    }
    float smin = dec_score((u32)(best >> 32));
    float thr = smin + MARGIN;
    int nc = 0;
#pragma unroll
    for (int i = 0; i < 16; i++)
      if (dec_score((u32)(key_s[t * 16 + i] >> 32)) <= thr) nc++;
    idx_s[t] = (int)(u32)(best & 0xffffffffull);
    commit_s[t] = znorm[r0 + t] + smin;
    if (nc > 1) {
      int pz = atomicAdd(&flagcnt_s, 1);
      flagrow_s[pz] = t;
    }
  }
  __syncthreads();

  if (t < 64) {
    int nf = flagcnt_s;
    for (int fi = 0; fi < nf; fi++) {
      int lr = flagrow_s[fi];
      int R = r0 + lr;
      u64 amin = ~0ull;
      for (int i = 0; i < 16; i++) {
        u64 k = key_s[lr * 16 + i];
        amin = k < amin ? k : amin;
      }
      float thr = dec_score((u32)(amin >> 32)) + MARGIN;
      float zn = znorm[R];
      const float* z = out + OFF_ZE + (size_t)R * DM;
      u64 bestk = ~0ull;
      for (int i = 0; i < 16; i++) {
        u64 k = key_s[lr * 16 + i];
        if (dec_score((u32)(k >> 32)) > thr) continue;
        int c = (int)(u32)(k & 0xffffffffull);
        const float* e = emb + (size_t)c * DM;
        float pdot = 0.f;
#pragma unroll
        for (int j = 0; j < 8; j++) pdot = fmaf(z[t + j * 64], e[t + j * 64], pdot);
#pragma unroll
        for (int m = 1; m < 64; m <<= 1) pdot += __shfl_xor(pdot, m, 64);
        float d = fmaf(-2.0f, pdot, zn) + enorm[c];
        u64 pk = ((u64)enc_score(d) << 32) | (u32)c;
        bestk = pk < bestk ? pk : bestk;
      }
      if (t == 0) {
        idx_s[lr] = (int)(u32)(bestk & 0xffffffffull);
        commit_s[lr] = dec_score((u32)(bestk >> 32));
      }
    }
  }
  __syncthreads();

  if (t < 16) {
    int R = r0 + t;
    int idx = idx_s[t];
    out[OFF_IDX + R] = (float)idx;
    idxws[R] = idx;
    atomicAdd(counts + idx, 1);
  }
  __syncthreads();
  for (int rr = 0; rr < 16; rr++) {
    int R = r0 + rr;
    const float* e = emb + (size_t)idx_s[rr] * DM;
    float* zq = out + OFF_ZQ + (size_t)R * DM;
#pragma unroll
    for (int j = 0; j < 2; j++) {
      int c = t + j * 256;
      zq[c] = e[c];
    }
  }
  if (t == 0) {
    float s = 0.f;
#pragma unroll
    for (int i = 0; i < 16; i++) s += commit_s[i];
    cpart[bid] = s;
  }
}

// ============================================================================
// LayerNorm (unchanged): z_e fp32, z1 f16 plane, znorm
// ============================================================================
__global__ __launch_bounds__(256) void k_ln3(float* __restrict__ ze,
                                             const float* __restrict__ g,
                                             const float* __restrict__ b,
                                             f16* __restrict__ z1,
                                             float* __restrict__ znorm) {
  int t = threadIdx.x, lane = t & 63, wid = t >> 6;
  int R = blockIdx.x * 4 + wid;
  float* row = ze + (size_t)R * DM;
  float v[8];
  float s = 0.f, sq = 0.f;
#pragma unroll
  for (int j = 0; j < 8; j++) {
    v[j] = row[lane + j * 64];
    s += v[j];
    sq = fmaf(v[j], v[j], sq);
  }
#pragma unroll
  for (int m = 1; m < 64; m <<= 1) {
    s += __shfl_xor(s, m, 64);
    sq += __shfl_xor(sq, m, 64);
  }
  float mu = s * (1.f / DM);
  float var = sq * (1.f / DM) - mu * mu;
  float rs = rsqrtf(var + 1e-5f);
  float zn = 0.f;
#pragma unroll
  for (int j = 0; j < 8; j++) {
    int c = lane + j * 64;
    float o = (v[j] - mu) * rs * g[c] + b[c];
    row[c] = o;
    z1[(size_t)R * DM + c] = (f16)o;
    zn = fmaf(o, o, zn);
  }
#pragma unroll
  for (int m = 1; m < 64; m <<= 1) zn += __shfl_xor(zn, m, 64);
  if (lane == 0) znorm[R] = zn;
}

// ============================================================================
// EMA tail (unchanged, proven)
// ============================================================================
__global__ __launch_bounds__(1024) void k_scan(const int* __restrict__ counts,
                                               const float* __restrict__ cs_in,
                                               float* __restrict__ out,
                                               int* __restrict__ starts,
                                               int* __restrict__ offw,
                                               float* __restrict__ csd,
                                               const float* __restrict__ cpart,
                                               int* __restrict__ chpfx,
                                               int* __restrict__ chcode) {
  __shared__ float f[1024];
  __shared__ int ib[1024];
  int t = threadIdx.x;
  f[t] = cpart[t] + cpart[t + 1024];
  __syncthreads();
  for (int s = 512; s > 0; s >>= 1) {
    if (t < s) f[t] += f[t + s];
    __syncthreads();
  }
  if (t == 0) out[OFF_CL] = f[0] * (1.f / ((float)NROWS * (float)DM));
  __syncthreads();

  int cnt = counts[t];
  float ncs = 0.99f * cs_in[t] + 0.01f * (float)cnt;
  out[OFF_NCS + t] = ncs;
  f[t] = ncs;
  __syncthreads();
  for (int s = 512; s > 0; s >>= 1) {
    if (t < s) f[t] += f[t + s];
    __syncthreads();
  }
  float n = f[0];
  csd[t] = (ncs + 1e-5f) / (n + (float)KC * 1e-5f) * n;
  ib[t] = cnt;
  __syncthreads();
  for (int s = 1; s < 1024; s <<= 1) {
    int y = (t >= s) ? ib[t - s] : 0;
    __syncthreads();
    ib[t] += y;
    __syncthreads();
  }
  int excl = ib[t] - cnt;
  starts[t] = excl;
  offw[t] = excl;
  int nch = (cnt + CHSZ - 1) / CHSZ;
  __syncthreads();
  ib[t] = nch;
  __syncthreads();
  for (int s = 1; s < 1024; s <<= 1) {
    int y = (t >= s) ? ib[t - s] : 0;
    __syncthreads();
    ib[t] += y;
    __syncthreads();
  }
  int chx = ib[t] - nch;
  chpfx[t] = chx;
  if (t == KC - 1) chpfx[KC] = ib[t];
  for (int j = 0; j < nch; j++) chcode[chx + j] = t;
}

__global__ __launch_bounds__(256) void k_scatter(const int* __restrict__ idxws,
                                                 int* __restrict__ offw,
                                                 int* __restrict__ rowlist) {
  int r = blockIdx.x * 256 + threadIdx.x;
  int idx = idxws[r];
  int pos = atomicAdd(offw + idx, 1);
  rowlist[pos] = r;
}

__global__ __launch_bounds__(128) void k_partsum(const int* __restrict__ chpfx,
                                                 const int* __restrict__ chcode,
                                                 const int* __restrict__ starts,
                                                 const int* __restrict__ counts,
                                                 const int* __restrict__ rowlist,
                                                 const float* __restrict__ out,
                                                 float* __restrict__ part) {
  int c = blockIdx.x, t = threadIdx.x;
  if (c >= chpfx[KC]) return;
  int code = chcode[c];
  int j = c - chpfx[code];
  int ofs = starts[code] + j * CHSZ;
  int len = min(CHSZ, counts[code] - j * CHSZ);
  __shared__ int rl[CHSZ];
  if (t < len) rl[t] = rowlist[ofs + t];
  __syncthreads();
  const float* zeb = out + OFF_ZE;
  float a0 = 0.f, a1 = 0.f, a2 = 0.f, a3 = 0.f;
  for (int i = 0; i < len; i++) {
    const float* z = zeb + (size_t)rl[i] * DM;
    a0 += z[t];
    a1 += z[t + 128];
    a2 += z[t + 256];
    a3 += z[t + 384];
  }
  float* pp = part + (size_t)c * DM;
  pp[t] = a0;
  pp[t + 128] = a1;
  pp[t + 256] = a2;
  pp[t + 384] = a3;
}

__global__ __launch_bounds__(128) void k_codesum2(const int* __restrict__ chpfx,
                                                  const float* __restrict__ part,
                                                  const float* __restrict__ ema_in,
                                                  const float* __restrict__ csd,
                                                  float* __restrict__ out) {
  int k = blockIdx.x, t = threadIdx.x;
  int base = chpfx[k], nch = chpfx[k + 1] - base;
  float a0 = 0.f, a1 = 0.f, a2 = 0.f, a3 = 0.f;
  for (int i = 0; i < nch; i++) {
    const float* pp = part + (size_t)(base + i) * DM;
    a0 += pp[t];
    a1 += pp[t + 128];
    a2 += pp[t + 256];
    a3 += pp[t + 384];
  }
  float cs = csd[k];
  float sum[4] = {a0, a1, a2, a3};
#pragma unroll
  for (int j = 0; j < 4; j++) {
    int c = t + j * 128;
    float e = 0.99f * ema_in[(size_t)k * DM + c] + 0.01f * sum[j];
    out[OFF_NEMA + (size_t)k * DM + c] = e;
    out[OFF_NE + (size_t)k * DM + c] = e / cs;
  }
}

// ============================================================================
extern "C" void kernel_launch(void* const* d_in, const int* in_sizes, int n_in,
                              void* d_out, int out_size, void* d_ws, size_t ws_size,
                              hipStream_t stream) {
  (void)in_sizes; (void)n_in; (void)out_size; (void)ws_size;
  const float* x = (const float*)d_in[0];
  const float* enc_w = (const float*)d_in[1];
  const float* enc_b = (const float*)d_in[2];
  const float* ln_g = (const float*)d_in[3];
  const float* ln_b = (const float*)d_in[4];
  const float* dec_w = (const float*)d_in[5];
  const float* dec_b = (const float*)d_in[6];
  const float* emb = (const float*)d_in[7];
  const float* cs_in = (const float*)d_in[8];
  const float* ema_in = (const float*)d_in[9];
  float* out = (float*)d_out;
  char* ws = (char*)d_ws;
  float* znorm = (float*)(ws + WS_ZNORM);
  int* idxws = (int*)(ws + WS_IDX);
  int* counts = (int*)(ws + WS_COUNTS);
  int* starts = (int*)(ws + WS_STARTS);
  int* offw = (int*)(ws + WS_OFFW);
  int* rowlist = (int*)(ws + WS_ROWLIST);
  float* csd = (float*)(ws + WS_CSD);
  float* enorm = (float*)(ws + WS_ENORM);
  u64* cand = (u64*)(ws + WS2_CAND);
  float* ED = (float*)(ws + WS2_CAND);   // reuses cand region after resolve
  f16* wt1 = (f16*)(ws + WS2_WT1);
  f16* wt2 = (f16*)(ws + WS2_WT2);
  f16* dT = (f16*)(ws + WS2_DT);
  f16* e1 = (f16*)(ws + WS2_E1);
  int* chpfx = (int*)(ws + WS3_CHPFX);
  int* chcode = (int*)(ws + WS3_CHCODE);
  float* cpart = (float*)(ws + WS3_CPART);
  float* part = (float*)(ws + WS3_PART);
  f16* z1 = (f16*)out;                 // scratch in x_recon region (overwritten by k_gatherx)

  k_prep<<<dim3(1796), dim3(256), 0, stream>>>(enc_w, dec_w, emb, wt1, wt2, dT,
                                               e1, enorm, counts);
  k_genc6<<<dim3(1024), dim3(512), 0, stream>>>(x, wt1, wt2, enc_b, out + OFF_ZE);
  k_ln3<<<dim3(8192), dim3(256), 0, stream>>>(out + OFF_ZE, ln_g, ln_b, z1, znorm);
  k_dist4<<<dim3(1024), dim3(512), 0, stream>>>(z1, e1, enorm, cand);
  k_resolve<<<dim3(2048), dim3(256), 0, stream>>>(cand, znorm, enorm, emb, out,
                                                  idxws, counts, cpart);
  k_edgemm<<<dim3(64), dim3(512), 0, stream>>>(e1, dT, dec_b, ED);
  k_scan<<<dim3(1), dim3(1024), 0, stream>>>(counts, cs_in, out, starts, offw, csd,
                                             cpart, chpfx, chcode);
  k_scatter<<<dim3(NROWS / 256), dim3(256), 0, stream>>>(idxws, offw, rowlist);
  k_partsum<<<dim3(MAXCH), dim3(128), 0, stream>>>(chpfx, chcode, starts, counts,
                                                   rowlist, out, part);
  k_codesum2<<<dim3(KC), dim3(128), 0, stream>>>(chpfx, part, ema_in, csd, out);
  k_gatherx<<<dim3(2048), dim3(256), 0, stream>>>(idxws, ED, out + OFF_XR);
}

// Round 14
// 329.606 us; speedup vs baseline: 1.3024x; 1.0062x over previous
//
#include <hip/hip_runtime.h>

typedef unsigned long long u64;
typedef unsigned int u32;
typedef _Float16 f16;
typedef _Float16 f16x8 __attribute__((ext_vector_type(8)));
typedef float f32x4 __attribute__((ext_vector_type(4)));

#define MFMA16(a, b, c) __builtin_amdgcn_mfma_f32_16x16x32_f16(a, b, c, 0, 0, 0)

#define NROWS 32768
#define DIN   1024
#define DM    512
#define KC    1024
#define SPLIT_SC  1024.0f
#define SPLIT_INV 0.0009765625f
#define CHSZ  32
#define MAXCH 2048
#define MARGIN 0.5f

// ---- output float offsets ----
#define OFF_XR   0ull
#define OFF_CL   33554432ull
#define OFF_IDX  33554433ull
#define OFF_ZE   33587201ull   // base %4==1 -> scalar access only
#define OFF_ZQ   50364417ull
#define OFF_NE   67141633ull
#define OFF_NCS  67665921ull
#define OFF_NEMA 67666945ull

// ---- workspace byte offsets ----
#define WS_ZNORM   2359296ull
#define WS_IDX     2490368ull
#define WS_COUNTS  2621440ull
#define WS_STARTS  2625536ull
#define WS_OFFW    2629632ull
#define WS_ROWLIST 2633728ull
#define WS_CSD     2764800ull
#define WS_ENORM   2769920ull
#define WS2_CAND   (4ull<<20)   // u64[32768*8] = 2MB; region reused as ED (4MB) after resolve
#define WS2_WT1    (36ull<<20)
#define WS2_WT2    (37ull<<20)
#define WS2_DT     (38ull<<20)
#define WS2_E1     (39ull<<20)
#define WS3_CHPFX  (41ull<<20)
#define WS3_CHCODE ((41ull<<20) + 8192)
#define WS3_CPART  ((41ull<<20) + 16384)
#define WS3_PART   ((41ull<<20) + 65536)

// ============================================================================
// LDS helpers (proven patterns)
// ============================================================================
__device__ inline void gload16(const f16* g, f16* l) {
  __builtin_amdgcn_global_load_lds((const __attribute__((address_space(1))) void*)g,
                                   (__attribute__((address_space(3))) void*)l, 16, 0, 0);
}

__device__ inline f16x8 ldfrag32(const f16* p, int row, int kc) {
  return *(const f16x8*)(p + row * 32 + ((kc ^ ((row >> 1) & 3)) << 3));
}

// stage a [128][32] f16 plane (8KB) with 512 threads (1 gload16 each)
__device__ inline void stage32(const f16* gbase, int ld, int row0, int k0,
                               f16* lds, int t) {
  int r = t >> 2, c = t & 3;
  int cs = c ^ ((r >> 1) & 3);
  gload16(gbase + (size_t)(row0 + r) * ld + k0 + cs * 8, lds + t * 8);
}

// stage a [256][32] f16 plane (16KB) with 512 threads (2 gload16 each)
__device__ inline void stageA256(const f16* gbase, int ld, int row0, int k0,
                                 f16* lds, int t) {
#pragma unroll
  for (int h = 0; h < 2; h++) {
    int e = t + h * 512;
    int r = e >> 2, c = e & 3;
    int cs = c ^ ((r >> 1) & 3);
    gload16(gbase + (size_t)(row0 + r) * ld + k0 + cs * 8, lds + e * 8);
  }
}

// monotone float->u32 map and inverse (argmin packing)
__device__ inline u32 enc_score(float s) {
  u32 kb = __float_as_uint(s);
  return (kb & 0x80000000u) ? ~kb : (kb | 0x80000000u);
}
__device__ inline float dec_score(u32 u) {
  u32 b = (u & 0x80000000u) ? (u & 0x7fffffffu) : ~u;
  return __uint_as_float(b);
}

// ============================================================================
// fused prep (unchanged, proven)
// ============================================================================
__global__ __launch_bounds__(256) void k_prep(const float* __restrict__ enc_w,
                                              const float* __restrict__ dec_w,
                                              const float* __restrict__ emb,
                                              f16* __restrict__ wt1,
                                              f16* __restrict__ wt2,
                                              f16* __restrict__ dT,
                                              f16* __restrict__ e1,
                                              float* __restrict__ enorm,
                                              int* __restrict__ counts) {
  __shared__ float tile[32][33];
  int bid = blockIdx.x, t = threadIdx.x;
  if (bid < 1024) {
    const float* W;
    f16 *o1, *o2;
    int K, N, bx, by;
    if (bid < 512) {
      W = enc_w; o1 = wt1; o2 = wt2; K = DIN; N = DM;
      bx = bid & 15; by = bid >> 4;
    } else {
      int b2 = bid - 512;
      W = dec_w; o1 = dT; o2 = nullptr; K = DM; N = DIN;
      bx = b2 & 31; by = b2 >> 5;
    }
    int tx = t & 31, ty = t >> 5;
    int nb = bx * 32, kb = by * 32;
#pragma unroll
    for (int i = 0; i < 32; i += 8)
      tile[ty + i][tx] = W[(size_t)(kb + ty + i) * N + nb + tx];
    __syncthreads();
#pragma unroll
    for (int i = 0; i < 32; i += 8) {
      float v = tile[tx][ty + i];
      f16 h = (f16)v;
      size_t o = (size_t)(nb + ty + i) * K + kb + tx;
      o1[o] = h;
      if (o2) o2[o] = (f16)((v - (float)h) * SPLIT_SC);
    }
  } else if (bid < 1536) {
    int tid = (bid - 1024) * 256 + t;
    for (int i = tid; i < KC * DM; i += 131072) e1[i] = (f16)emb[i];
  } else if (bid < 1792) {
    int k = (bid - 1536) * 4 + (t >> 6), lane = t & 63;
    float s = 0.f;
#pragma unroll
    for (int j = 0; j < 8; j++) {
      float v = emb[(size_t)k * DM + lane + j * 64];
      s = fmaf(v, v, s);
    }
#pragma unroll
    for (int m = 1; m < 64; m <<= 1) s += __shfl_xor(s, m, 64);
    if (lane == 0) enorm[k] = s;
  } else {
    int i = (bid - 1792) * 256 + t;
    if (i < KC) counts[i] = 0;
  }
}

// ============================================================================
// encoder GEMM v7: genc6 + 3-buffered B (80KB, 2 blocks/CU). The single
// vmcnt(4) per iter retires {B(it+1), av(it+1)}, both issued a FULL iteration
// earlier -> HBM latency covered. Accumulation order bit-identical to genc4/6.
// Ledger (4 vmem ops/iter: 2 B-stage + 2 av-loads):
//   prologue: B(0),av(0),B(1),av(1) issued (8 ops) -> vmcnt(4) retires
//             B(0)+av(0); GCONV av(0); lgkm0; barrier.
//   iter it:  stage B(it+2)->B[(it+2)%3]; load av(it+2); compute(it);
//             vmcnt(4) [it=30: vmcnt(0)] retires B(it+1)+av(it+1);
//             GCONV av(it+1)->A[(it+1)&1]; lgkm0; barrier.
// Hazards: stage targets (it+2)%3 vs reads it%3 (disjoint mod 3); convert
// writes A[(it+1)&1] vs reads A[it&1]; foreign reads sealed by prev barrier.
// ============================================================================
__global__ __launch_bounds__(512, 4) void k_genc7(const float* __restrict__ x,
                                                  const f16* __restrict__ wt1,
                                                  const f16* __restrict__ wt2,
                                                  const float* __restrict__ bias,
                                                  float* __restrict__ dst) {
  __shared__ __align__(16) f16 A1[2][128 * 32], A2[2][128 * 32];   // 32KB
  __shared__ __align__(16) f16 B1[3][128 * 32], B2[3][128 * 32];   // 48KB
  int t = threadIdx.x, lane = t & 63, wid = t >> 6;
  int wm = wid >> 2, wn = wid & 3;
  int l = blockIdx.x;
  int xcd = l & 7, s = l >> 3, ct = s & 3;
  int p = ((s >> 2) << 3) | xcd;
  int m0 = p * 128, n0 = ct * 128;
  int r = t >> 2, cg = t & 3;
  int cslot = cg ^ ((r >> 1) & 3);
  const float* ax = x + (size_t)(m0 + r) * DIN + cg * 8;
  f32x4 accA[4][2] = {}, accB[4][2] = {};

#define GCONV(v0, v1, buf)                                                  \
  {                                                                         \
    float a_[8] = {v0.x, v0.y, v0.z, v0.w, v1.x, v1.y, v1.z, v1.w};         \
    f16 h1_[8], h2_[8];                                                     \
    _Pragma("unroll") for (int j_ = 0; j_ < 8; j_++) {                      \
      f16 h_ = (f16)a_[j_];                                                 \
      h1_[j_] = h_;                                                         \
      h2_[j_] = (f16)((a_[j_] - (float)h_) * SPLIT_SC);                     \
    }                                                                       \
    *(f16x8*)(A1[buf] + r * 32 + cslot * 8) = *(f16x8*)h1_;                 \
    *(f16x8*)(A2[buf] + r * 32 + cslot * 8) = *(f16x8*)h2_;                 \
  }

#define GCOMP(abuf, bbuf)                                                   \
  {                                                                         \
    int kc_ = lane >> 4;                                                    \
    f16x8 a1f[4], a2f[4], b1f[2], b2f[2];                                   \
    _Pragma("unroll") for (int m_ = 0; m_ < 4; m_++) {                      \
      int row_ = wm * 64 + m_ * 16 + (lane & 15);                           \
      a1f[m_] = ldfrag32(A1[abuf], row_, kc_);                              \
      a2f[m_] = ldfrag32(A2[abuf], row_, kc_);                              \
    }                                                                       \
    _Pragma("unroll") for (int n_ = 0; n_ < 2; n_++) {                      \
      int row_ = wn * 32 + n_ * 16 + (lane & 15);                           \
      b1f[n_] = ldfrag32(B1[bbuf], row_, kc_);                              \
      b2f[n_] = ldfrag32(B2[bbuf], row_, kc_);                              \
    }                                                                       \
    _Pragma("unroll") for (int m_ = 0; m_ < 4; m_++)                        \
      _Pragma("unroll") for (int n_ = 0; n_ < 2; n_++) {                    \
        accA[m_][n_] = MFMA16(a1f[m_], b1f[n_], accA[m_][n_]);              \
        accB[m_][n_] = MFMA16(a1f[m_], b2f[n_], accB[m_][n_]);              \
        accB[m_][n_] = MFMA16(a2f[m_], b1f[n_], accB[m_][n_]);              \
      }                                                                     \
  }

  // prologue: B(0), av(0), B(1), av(1)
  stage32(wt1, DIN, n0, 0, B1[0], t);
  stage32(wt2, DIN, n0, 0, B2[0], t);
  float4 c0 = *(const float4*)(ax);
  float4 c1 = *(const float4*)(ax + 4);
  stage32(wt1, DIN, n0, 32, B1[1], t);
  stage32(wt2, DIN, n0, 32, B2[1], t);
  float4 n0v = *(const float4*)(ax + 32);
  float4 n1v = *(const float4*)(ax + 36);
  asm volatile("s_waitcnt vmcnt(4)" ::: "memory");   // B(0)+av(0) retired
  GCONV(c0, c1, 0);
  asm volatile("s_waitcnt lgkmcnt(0)" ::: "memory");
  __builtin_amdgcn_sched_barrier(0);
  __builtin_amdgcn_s_barrier();
  asm volatile("" ::: "memory");

  for (int it = 0; it < 32; ++it) {
    float4 f0, f1;
    if (it + 2 < 32) {                              // B(it+2), av(it+2)
      stage32(wt1, DIN, n0, (it + 2) * 32, B1[(it + 2) % 3], t);
      stage32(wt2, DIN, n0, (it + 2) * 32, B2[(it + 2) % 3], t);
      f0 = *(const float4*)(ax + (it + 2) * 32);
      f1 = *(const float4*)(ax + (it + 2) * 32 + 4);
    }
    GCOMP(it & 1, it % 3);                          // compute(it)
    if (it + 1 < 32) {
      if (it <= 29) {                               // retire B(it+1)+av(it+1)
        asm volatile("s_waitcnt vmcnt(4)" ::: "memory");
      } else {
        asm volatile("s_waitcnt vmcnt(0)" ::: "memory");
      }
      GCONV(n0v, n1v, (it + 1) & 1);
      asm volatile("s_waitcnt lgkmcnt(0)" ::: "memory");
      __builtin_amdgcn_sched_barrier(0);
      __builtin_amdgcn_s_barrier();
      asm volatile("" ::: "memory");
    }
    n0v = f0; n1v = f1;
  }
#undef GCONV
#undef GCOMP

#pragma unroll
  for (int m = 0; m < 4; m++)
#pragma unroll
    for (int n = 0; n < 2; n++)
#pragma unroll
      for (int j = 0; j < 4; j++) {
        int row = m0 + wm * 64 + m * 16 + (lane >> 4) * 4 + j;
        int col = n0 + wn * 32 + n * 16 + (lane & 15);
        dst[(size_t)row * DM + col] = accA[m][n][j] + SPLIT_INV * accB[m][n][j] + bias[col];
      }
}

// ============================================================================
// distance GEMM v5: role-swapped dist4 — 128 rows x 256 cols per block
// (z1 HBM re-reads 8x -> 4x). A[3][128*32]+B[3][256*32]=72KB, 3-op/iter
// vmcnt(3) schedule (proven). Waves 2r x 4c, wave tile 64x64, 16 MFMA/iter.
// Epilogue: top-2 per 256-col tile -> cand[row][ct*2], stride 8.
// ============================================================================
__global__ __launch_bounds__(512, 4) void k_dist5(const f16* __restrict__ z1,
                                                  const f16* __restrict__ e1,
                                                  const float* __restrict__ enorm,
                                                  u64* __restrict__ cand) {
  __shared__ __align__(16) f16 A[3][128 * 32];   // 24KB
  __shared__ __align__(16) f16 B[3][256 * 32];   // 48KB
  int t = threadIdx.x, lane = t & 63, wid = t >> 6;
  int wr = wid >> 2, wc = wid & 3;               // 2 row-waves x 4 col-waves
  int l = blockIdx.x;
  int xcd = l & 7, s = l >> 3, ct = s & 3;       // 4 col tiles of 256
  int p = ((s >> 2) << 3) | xcd;                 // 256 row panels of 128
  int r0 = p * 128, c0 = ct * 256;
  f32x4 acc[4][4] = {};
  int kc = lane >> 4;

  stage32(z1, DM, r0, 0, A[0], t);
  stageA256(e1, DM, c0, 0, B[0], t);

  for (int it = 0; it < 16; ++it) {
    int buf = it % 3;
    if (it < 15) {
      int nb = (it + 1) % 3;
      int k0n = (it + 1) * 32;
      stage32(z1, DM, r0, k0n, A[nb], t);
      stageA256(e1, DM, c0, k0n, B[nb], t);
      asm volatile("s_waitcnt vmcnt(3)" ::: "memory");   // retire stage(it)
    } else {
      asm volatile("s_waitcnt vmcnt(0)" ::: "memory");
    }
    __builtin_amdgcn_sched_barrier(0);
    __builtin_amdgcn_s_barrier();
    asm volatile("" ::: "memory");
    f16x8 af[4], bf[4];
#pragma unroll
    for (int m = 0; m < 4; m++)
      af[m] = ldfrag32(A[buf], wr * 64 + m * 16 + (lane & 15), kc);
#pragma unroll
    for (int n = 0; n < 4; n++)
      bf[n] = ldfrag32(B[buf], wc * 64 + n * 16 + (lane & 15), kc);
#pragma unroll
    for (int m = 0; m < 4; m++)
#pragma unroll
      for (int n = 0; n < 4; n++) acc[m][n] = MFMA16(af[m], bf[n], acc[m][n]);
  }

  __syncthreads();                                // all LDS reads done
  u64 (*cand_s)[8] = (u64 (*)[8])(&A[0][0]);      // 8KB, aliases dead A
  float en[4];
#pragma unroll
  for (int n = 0; n < 4; n++)
    en[n] = enorm[c0 + wc * 64 + n * 16 + (lane & 15)];
#pragma unroll
  for (int m = 0; m < 4; m++)
#pragma unroll
    for (int j = 0; j < 4; j++) {
      int r_l = wr * 64 + m * 16 + (lane >> 4) * 4 + j;   // 0..127
      u64 lo = ~0ull, hi = ~0ull;
#pragma unroll
      for (int n = 0; n < 4; n++) {
        int col = c0 + wc * 64 + n * 16 + (lane & 15);
        float sc = fmaf(-2.0f, acc[m][n][j], en[n]);
        u64 k = ((u64)enc_score(sc) << 32) | (u32)col;
        if (k < lo) { hi = lo; lo = k; }
        else if (k < hi) { hi = k; }
      }
#pragma unroll
      for (int msk = 1; msk < 16; msk <<= 1) {
        u64 lo2 = __shfl_xor(lo, msk, 64);
        u64 hi2 = __shfl_xor(hi, msk, 64);
        u64 nlo = lo < lo2 ? lo : lo2;
        u64 losr = lo < lo2 ? lo2 : lo;
        u64 nh = hi < hi2 ? hi : hi2;
        hi = losr < nh ? losr : nh;
        lo = nlo;
      }
      if ((lane & 15) == 0) {
        cand_s[r_l][wc * 2] = lo;
        cand_s[r_l][wc * 2 + 1] = hi;
      }
    }
  __syncthreads();
  if (t < 128) {
    u64 b0 = ~0ull, b1 = ~0ull;                   // block top-2 over 8 keys
#pragma unroll
    for (int i = 0; i < 8; i++) {
      u64 k = cand_s[t][i];
      if (k < b0) { b1 = b0; b0 = k; }
      else if (k < b1) { b1 = k; }
    }
    u64* dst = cand + ((size_t)(r0 + t) * 8 + ct * 2);
    dst[0] = b0;
    dst[1] = b1;
  }
}

// ============================================================================
// resolve v5: 32 rows/block over 8 candidate keys; exact fp32 rescore of
// flagged rows (same margin logic as proven 16-key version).
// ============================================================================
__global__ __launch_bounds__(256) void k_resolve5(const u64* __restrict__ cand,
                                                  const float* __restrict__ znorm,
                                                  const float* __restrict__ enorm,
                                                  const float* __restrict__ emb,
                                                  float* __restrict__ out,
                                                  int* __restrict__ idxws,
                                                  int* __restrict__ counts,
                                                  float* __restrict__ cpart) {
  int t = threadIdx.x, bid = blockIdx.x;
  int r0 = bid * 32;
  __shared__ u64 key_s[256];
  __shared__ int idx_s[32];
  __shared__ float commit_s[32];
  __shared__ int flagcnt_s;
  __shared__ int flagrow_s[32];
  key_s[t] = cand[(size_t)r0 * 8 + t];
  if (t == 0) flagcnt_s = 0;
  __syncthreads();

  if (t < 32) {
    u64 best = ~0ull;
#pragma unroll
    for (int i = 0; i < 8; i++) {
      u64 k = key_s[t * 8 + i];
      best = k < best ? k : best;
    }
    float smin = dec_score((u32)(best >> 32));
    float thr = smin + MARGIN;
    int nc = 0;
#pragma unroll
    for (int i = 0; i < 8; i++)
      if (dec_score((u32)(key_s[t * 8 + i] >> 32)) <= thr) nc++;
    idx_s[t] = (int)(u32)(best & 0xffffffffull);
    commit_s[t] = znorm[r0 + t] + smin;
    if (nc > 1) {
      int pz = atomicAdd(&flagcnt_s, 1);
      flagrow_s[pz] = t;
    }
  }
  __syncthreads();

  if (t < 64) {                                   // wave 0: exact rescore
    int nf = flagcnt_s;
    for (int fi = 0; fi < nf; fi++) {
      int lr = flagrow_s[fi];
      int R = r0 + lr;
      u64 amin = ~0ull;
      for (int i = 0; i < 8; i++) {
        u64 k = key_s[lr * 8 + i];
        amin = k < amin ? k : amin;
      }
      float thr = dec_score((u32)(amin >> 32)) + MARGIN;
      float zn = znorm[R];
      const float* z = out + OFF_ZE + (size_t)R * DM;
      u64 bestk = ~0ull;
      for (int i = 0; i < 8; i++) {
        u64 k = key_s[lr * 8 + i];
        if (dec_score((u32)(k >> 32)) > thr) continue;
        int c = (int)(u32)(k & 0xffffffffull);
        const float* e = emb + (size_t)c * DM;
        float pdot = 0.f;
#pragma unroll
        for (int j = 0; j < 8; j++) pdot = fmaf(z[t + j * 64], e[t + j * 64], pdot);
#pragma unroll
        for (int m = 1; m < 64; m <<= 1) pdot += __shfl_xor(pdot, m, 64);
        float d = fmaf(-2.0f, pdot, zn) + enorm[c];
        u64 pk = ((u64)enc_score(d) << 32) | (u32)c;
        bestk = pk < bestk ? pk : bestk;
      }
      if (t == 0) {
        idx_s[lr] = (int)(u32)(bestk & 0xffffffffull);
        commit_s[lr] = dec_score((u32)(bestk >> 32));
      }
    }
  }
  __syncthreads();

  if (t < 32) {
    int R = r0 + t;
    int idx = idx_s[t];
    out[OFF_IDX + R] = (float)idx;
    idxws[R] = idx;
    atomicAdd(counts + idx, 1);
  }
  __syncthreads();
  for (int rr = 0; rr < 32; rr++) {
    int R = r0 + rr;
    const float* e = emb + (size_t)idx_s[rr] * DM;
    float* zq = out + OFF_ZQ + (size_t)R * DM;
#pragma unroll
    for (int j = 0; j < 2; j++) {
      int c = t + j * 256;
      zq[c] = e[c];
    }
  }
  if (t == 0) {
    float s = 0.f;
#pragma unroll
    for (int i = 0; i < 32; i++) s += commit_s[i];
    cpart[bid] = s;
  }
}

// ============================================================================
// ED GEMM (unchanged): ED = e1 @ dT + dec_b; x_recon[r] = ED[idx[r]]
// ============================================================================
__global__ __launch_bounds__(512) void k_edgemm(const f16* __restrict__ e1,
                                                const f16* __restrict__ dT,
                                                const float* __restrict__ bias,
                                                float* __restrict__ ED) {
  __shared__ __align__(16) f16 A[3][128 * 32], B[3][128 * 32];
  int t = threadIdx.x, lane = t & 63, wid = t >> 6;
  int wm = wid >> 2, wn = wid & 3;
  int r0 = (blockIdx.x >> 3) * 128, c0 = (blockIdx.x & 7) * 128;
  f32x4 acc[4][2] = {};
  int kc = lane >> 4;

  stage32(e1, DM, r0, 0, A[0], t);
  stage32(dT, DM, c0, 0, B[0], t);

  for (int it = 0; it < 16; ++it) {
    int buf = it % 3;
    if (it < 15) {
      int nb = (it + 1) % 3;
      int k0n = (it + 1) * 32;
      stage32(e1, DM, r0, k0n, A[nb], t);
      stage32(dT, DM, c0, k0n, B[nb], t);
      asm volatile("s_waitcnt vmcnt(2)" ::: "memory");
    } else {
      asm volatile("s_waitcnt vmcnt(0)" ::: "memory");
    }
    __builtin_amdgcn_sched_barrier(0);
    __builtin_amdgcn_s_barrier();
    asm volatile("" ::: "memory");
    f16x8 af[4], bf[2];
#pragma unroll
    for (int m = 0; m < 4; m++)
      af[m] = ldfrag32(A[buf], wm * 64 + m * 16 + (lane & 15), kc);
#pragma unroll
    for (int n = 0; n < 2; n++)
      bf[n] = ldfrag32(B[buf], wn * 32 + n * 16 + (lane & 15), kc);
#pragma unroll
    for (int m = 0; m < 4; m++)
#pragma unroll
      for (int n = 0; n < 2; n++) acc[m][n] = MFMA16(af[m], bf[n], acc[m][n]);
  }

#pragma unroll
  for (int m = 0; m < 4; m++)
#pragma unroll
    for (int n = 0; n < 2; n++)
#pragma unroll
      for (int j = 0; j < 4; j++) {
        int row = r0 + wm * 64 + m * 16 + (lane >> 4) * 4 + j;
        int col = c0 + wn * 32 + n * 16 + (lane & 15);
        ED[(size_t)row * DIN + col] = acc[m][n][j] + bias[col];
      }
}

__global__ __launch_bounds__(256) void k_gatherx(const int* __restrict__ idxws,
                                                 const float* __restrict__ ED,
                                                 float* __restrict__ xr) {
  int t = threadIdx.x, r0 = blockIdx.x * 16;
  __shared__ int idx_s[16];
  if (t < 16) idx_s[t] = idxws[r0 + t];
  __syncthreads();
  for (int rr = 0; rr < 16; rr++) {
    int R = r0 + rr;
    const float4* src = (const float4*)(ED + (size_t)idx_s[rr] * DIN);
    float4* dst = (float4*)(xr + (size_t)R * DIN);
    dst[t] = src[t];
  }
}

// ============================================================================
// LayerNorm (unchanged): z_e fp32, z1 f16 plane, znorm
// ============================================================================
__global__ __launch_bounds__(256) void k_ln3(float* __restrict__ ze,
                                             const float* __restrict__ g,
                                             const float* __restrict__ b,
                                             f16* __restrict__ z1,
                                             float* __restrict__ znorm) {
  int t = threadIdx.x, lane = t & 63, wid = t >> 6;
  int R = blockIdx.x * 4 + wid;
  float* row = ze + (size_t)R * DM;
  float v[8];
  float s = 0.f, sq = 0.f;
#pragma unroll
  for (int j = 0; j < 8; j++) {
    v[j] = row[lane + j * 64];
    s += v[j];
    sq = fmaf(v[j], v[j], sq);
  }
#pragma unroll
  for (int m = 1; m < 64; m <<= 1) {
    s += __shfl_xor(s, m, 64);
    sq += __shfl_xor(sq, m, 64);
  }
  float mu = s * (1.f / DM);
  float var = sq * (1.f / DM) - mu * mu;
  float rs = rsqrtf(var + 1e-5f);
  float zn = 0.f;
#pragma unroll
  for (int j = 0; j < 8; j++) {
    int c = lane + j * 64;
    float o = (v[j] - mu) * rs * g[c] + b[c];
    row[c] = o;
    z1[(size_t)R * DM + c] = (f16)o;
    zn = fmaf(o, o, zn);
  }
#pragma unroll
  for (int m = 1; m < 64; m <<= 1) zn += __shfl_xor(zn, m, 64);
  if (lane == 0) znorm[R] = zn;
}

// ============================================================================
// EMA tail (proven; cpart now 1024 entries)
// ============================================================================
__global__ __launch_bounds__(1024) void k_scan(const int* __restrict__ counts,
                                               const float* __restrict__ cs_in,
                                               float* __restrict__ out,
                                               int* __restrict__ starts,
                                               int* __restrict__ offw,
                                               float* __restrict__ csd,
                                               const float* __restrict__ cpart,
                                               int* __restrict__ chpfx,
                                               int* __restrict__ chcode) {
  __shared__ float f[1024];
  __shared__ int ib[1024];
  int t = threadIdx.x;
  f[t] = cpart[t];
  __syncthreads();
  for (int s = 512; s > 0; s >>= 1) {
    if (t < s) f[t] += f[t + s];
    __syncthreads();
  }
  if (t == 0) out[OFF_CL] = f[0] * (1.f / ((float)NROWS * (float)DM));
  __syncthreads();

  int cnt = counts[t];
  float ncs = 0.99f * cs_in[t] + 0.01f * (float)cnt;
  out[OFF_NCS + t] = ncs;
  f[t] = ncs;
  __syncthreads();
  for (int s = 512; s > 0; s >>= 1) {
    if (t < s) f[t] += f[t + s];
    __syncthreads();
  }
  float n = f[0];
  csd[t] = (ncs + 1e-5f) / (n + (float)KC * 1e-5f) * n;
  ib[t] = cnt;
  __syncthreads();
  for (int s = 1; s < 1024; s <<= 1) {
    int y = (t >= s) ? ib[t - s] : 0;
    __syncthreads();
    ib[t] += y;
    __syncthreads();
  }
  int excl = ib[t] - cnt;
  starts[t] = excl;
  offw[t] = excl;
  int nch = (cnt + CHSZ - 1) / CHSZ;
  __syncthreads();
  ib[t] = nch;
  __syncthreads();
  for (int s = 1; s < 1024; s <<= 1) {
    int y = (t >= s) ? ib[t - s] : 0;
    __syncthreads();
    ib[t] += y;
    __syncthreads();
  }
  int chx = ib[t] - nch;
  chpfx[t] = chx;
  if (t == KC - 1) chpfx[KC] = ib[t];
  for (int j = 0; j < nch; j++) chcode[chx + j] = t;
}

__global__ __launch_bounds__(256) void k_scatter(const int* __restrict__ idxws,
                                                 int* __restrict__ offw,
                                                 int* __restrict__ rowlist) {
  int r = blockIdx.x * 256 + threadIdx.x;
  int idx = idxws[r];
  int pos = atomicAdd(offw + idx, 1);
  rowlist[pos] = r;
}

__global__ __launch_bounds__(128) void k_partsum(const int* __restrict__ chpfx,
                                                 const int* __restrict__ chcode,
                                                 const int* __restrict__ starts,
                                                 const int* __restrict__ counts,
                                                 const int* __restrict__ rowlist,
                                                 const float* __restrict__ out,
                                                 float* __restrict__ part) {
  int c = blockIdx.x, t = threadIdx.x;
  if (c >= chpfx[KC]) return;
  int code = chcode[c];
  int j = c - chpfx[code];
  int ofs = starts[code] + j * CHSZ;
  int len = min(CHSZ, counts[code] - j * CHSZ);
  __shared__ int rl[CHSZ];
  if (t < len) rl[t] = rowlist[ofs + t];
  __syncthreads();
  const float* zeb = out + OFF_ZE;
  float a0 = 0.f, a1 = 0.f, a2 = 0.f, a3 = 0.f;
  for (int i = 0; i < len; i++) {
    const float* z = zeb + (size_t)rl[i] * DM;
    a0 += z[t];
    a1 += z[t + 128];
    a2 += z[t + 256];
    a3 += z[t + 384];
  }
  float* pp = part + (size_t)c * DM;
  pp[t] = a0;
  pp[t + 128] = a1;
  pp[t + 256] = a2;
  pp[t + 384] = a3;
}

__global__ __launch_bounds__(128) void k_codesum2(const int* __restrict__ chpfx,
                                                  const float* __restrict__ part,
                                                  const float* __restrict__ ema_in,
                                                  const float* __restrict__ csd,
                                                  float* __restrict__ out) {
  int k = blockIdx.x, t = threadIdx.x;
  int base = chpfx[k], nch = chpfx[k + 1] - base;
  float a0 = 0.f, a1 = 0.f, a2 = 0.f, a3 = 0.f;
  for (int i = 0; i < nch; i++) {
    const float* pp = part + (size_t)(base + i) * DM;
    a0 += pp[t];
    a1 += pp[t + 128];
    a2 += pp[t + 256];
    a3 += pp[t + 384];
  }
  float cs = csd[k];
  float sum[4] = {a0, a1, a2, a3};
#pragma unroll
  for (int j = 0; j < 4; j++) {
    int c = t + j * 128;
    float e = 0.99f * ema_in[(size_t)k * DM + c] + 0.01f * sum[j];
    out[OFF_NEMA + (size_t)k * DM + c] = e;
    out[OFF_NE + (size_t)k * DM + c] = e / cs;
  }
}

// ============================================================================
extern "C" void kernel_launch(void* const* d_in, const int* in_sizes, int n_in,
                              void* d_out, int out_size, void* d_ws, size_t ws_size,
                              hipStream_t stream) {
  (void)in_sizes; (void)n_in; (void)out_size; (void)ws_size;
  const float* x = (const float*)d_in[0];
  const float* enc_w = (const float*)d_in[1];
  const float* enc_b = (const float*)d_in[2];
  const float* ln_g = (const float*)d_in[3];
  const float* ln_b = (const float*)d_in[4];
  const float* dec_w = (const float*)d_in[5];
  const float* dec_b = (const float*)d_in[6];
  const float* emb = (const float*)d_in[7];
  const float* cs_in = (const float*)d_in[8];
  const float* ema_in = (const float*)d_in[9];
  float* out = (float*)d_out;
  char* ws = (char*)d_ws;
  float* znorm = (float*)(ws + WS_ZNORM);
  int* idxws = (int*)(ws + WS_IDX);
  int* counts = (int*)(ws + WS_COUNTS);
  int* starts = (int*)(ws + WS_STARTS);
  int* offw = (int*)(ws + WS_OFFW);
  int* rowlist = (int*)(ws + WS_ROWLIST);
  float* csd = (float*)(ws + WS_CSD);
  float* enorm = (float*)(ws + WS_ENORM);
  u64* cand = (u64*)(ws + WS2_CAND);
  float* ED = (float*)(ws + WS2_CAND);   // reuses cand region after resolve
  f16* wt1 = (f16*)(ws + WS2_WT1);
  f16* wt2 = (f16*)(ws + WS2_WT2);
  f16* dT = (f16*)(ws + WS2_DT);
  f16* e1 = (f16*)(ws + WS2_E1);
  int* chpfx = (int*)(ws + WS3_CHPFX);
  int* chcode = (int*)(ws + WS3_CHCODE);
  float* cpart = (float*)(ws + WS3_CPART);
  float* part = (float*)(ws + WS3_PART);
  f16* z1 = (f16*)out;                 // scratch in x_recon region (overwritten by k_gatherx)

  k_prep<<<dim3(1796), dim3(256), 0, stream>>>(enc_w, dec_w, emb, wt1, wt2, dT,
                                               e1, enorm, counts);
  k_genc7<<<dim3(1024), dim3(512), 0, stream>>>(x, wt1, wt2, enc_b, out + OFF_ZE);
  k_ln3<<<dim3(8192), dim3(256), 0, stream>>>(out + OFF_ZE, ln_g, ln_b, z1, znorm);
  k_dist5<<<dim3(1024), dim3(512), 0, stream>>>(z1, e1, enorm, cand);
  k_resolve5<<<dim3(1024), dim3(256), 0, stream>>>(cand, znorm, enorm, emb, out,
                                                   idxws, counts, cpart);
  k_edgemm<<<dim3(64), dim3(512), 0, stream>>>(e1, dT, dec_b, ED);
  k_scan<<<dim3(1), dim3(1024), 0, stream>>>(counts, cs_in, out, starts, offw, csd,
                                             cpart, chpfx, chcode);
  k_scatter<<<dim3(NROWS / 256), dim3(256), 0, stream>>>(idxws, offw, rowlist);
  k_partsum<<<dim3(MAXCH), dim3(128), 0, stream>>>(chpfx, chcode, starts, counts,
                                                   rowlist, out, part);
  k_codesum2<<<dim3(KC), dim3(128), 0, stream>>>(chpfx, part, ema_in, csd, out);
  k_gatherx<<<dim3(2048), dim3(256), 0, stream>>>(idxws, ED, out + OFF_XR);
}